// Round 7
// baseline (356.972 us; speedup 1.0000x reference)
//
#include <hip/hip_runtime.h>
#include <hip/hip_bf16.h>
#include <cstdio>

// BlockAxialUp on MI355X, round 7:
//  - O stays in registers; proj B-operand built via in-register pack+shfl
//    (removes 2 barriers/head + the O LDS round trip + proj LDS reads)
//  - both directions in ONE 1024-block launch (blockIdx.y = dir), separate
//    accumulators; conv does relu(a0+a1)
//
// ws layout (bytes):
//   0         wqkvT_h bf16 [768][256] (q 0:256, k 256:512, v 512:768)
//   393216    wqkvT_w
//   786432    woT_h  bf16 [256][256]
//   917504    woT_w
//   1048576   convT  bf16 [128][640]
//   1245184   xu     bf16 [65536][256]
//   34799616  ytmp   f32  [65536][128]
//   68354048  partial f32 [128][128][2]
//   68485120  stats  f32  [128][2]
//   68486144  accb1  bf16 [65536][256]   (dir-1 axial output)
// accb0 (dir-0) lives in d_out; final f32 output overwrites it after conv.

typedef short bf16x8 __attribute__((ext_vector_type(8)));
typedef short bf16x4 __attribute__((ext_vector_type(4)));
typedef float f32x4 __attribute__((ext_vector_type(4)));
typedef unsigned int u32x4 __attribute__((ext_vector_type(4)));

#define MFMA16(a, b, c) __builtin_amdgcn_mfma_f32_16x16x32_bf16((a), (b), (c), 0, 0, 0)

__device__ __forceinline__ short f2bf(float v) {
  __hip_bfloat16 h = __float2bfloat16(v);
  union { __hip_bfloat16 h; short s; } u; u.h = h; return u.s;
}
__device__ __forceinline__ float bf2f(short s) {
  return __uint_as_float(((unsigned int)(unsigned short)s) << 16);
}
__device__ __forceinline__ unsigned pk2(float lo, float hi) {
  return ((unsigned)(unsigned short)f2bf(lo)) |
         (((unsigned)(unsigned short)f2bf(hi)) << 16);
}
// XOR swizzle, granule = 8 shorts (16 B)
__device__ __forceinline__ int swz(int row, int col) {
  return col ^ ((row & 7) << 3);
}

// ---------------- fused weight prep: dst[n][k] = bf16(src[k][n]) ------------
struct WtAll {
  const float* src[7];
  short* dst[7];
  int K[7], N[7], tile0[7];
};

__global__ __launch_bounds__(256) void k_wt_all(WtAll P) {
  const int bid = blockIdx.x;
  int i = 0;
#pragma unroll
  for (int j = 1; j < 7; j++) if (bid >= P.tile0[j]) i = j;
  const float* src = P.src[i];
  short* dst = P.dst[i];
  const int K = P.K[i], N = P.N[i];
  const int local = bid - P.tile0[i];
  const int ktiles = K >> 5;
  const int nt = local / ktiles, kt = local - nt * ktiles;
  const int k0 = kt * 32, n0 = nt * 32;
  __shared__ float tile[32][33];
  const int tx = threadIdx.x & 31, ty = threadIdx.x >> 5;
#pragma unroll
  for (int r = 0; r < 4; r++)
    tile[ty + r * 8][tx] = src[(size_t)(k0 + ty + r * 8) * N + n0 + tx];
  __syncthreads();
#pragma unroll
  for (int r = 0; r < 4; r++)
    dst[(size_t)(n0 + ty + r * 8) * K + k0 + tx] = f2bf(tile[tx][ty + r * 8]);
}

// ---------------- upsample 2x bilinear align_corners --------------------
__global__ __launch_bounds__(256) void k_upsample(const float* __restrict__ x,
                                                  short* __restrict__ xu) {
  __shared__ float ldsV[64][65];
  const int bh = blockIdx.x, z = blockIdx.y;
  const int b = bh >> 7, h = bh & 127;
  const float chf = h * (63.0f / 127.0f);
  int i0 = (int)chf; if (i0 > 62) i0 = 62;
  const float wh = chf - (float)i0;
  const int t = threadIdx.x;
  const int cbase = z * 64;
  const float* xb = x + ((size_t)(b * 256 + cbase) * 64 + i0) * 64;
#pragma unroll
  for (int p = 0; p < 16; p++) {
    const int li = p * 256 + t;
    const int c = li >> 6, w = li & 63;
    const float* px = xb + (size_t)c * 4096 + w;
    const float v0 = px[0], v1 = px[64];
    ldsV[c][w] = v0 * (1.f - wh) + v1 * wh;
  }
  __syncthreads();
  const int cg = t & 7, wi = t >> 3;
  short* xout = xu + (size_t)(bh * 128) * 256 + cbase + cg * 8;
#pragma unroll
  for (int p = 0; p < 4; p++) {
    const int w = p * 32 + wi;
    const float cwf = w * (63.0f / 127.0f);
    int j0 = (int)cwf; if (j0 > 62) j0 = 62;
    const float ww = cwf - (float)j0;
    bf16x8 o;
#pragma unroll
    for (int u = 0; u < 8; u++) {
      const float v0 = ldsV[cg * 8 + u][j0], v1 = ldsV[cg * 8 + u][j0 + 1];
      o[u] = f2bf(v0 * (1.f - ww) + v1 * ww);
    }
    *(bf16x8*)(xout + (size_t)w * 256) = o;
  }
}

// ---------------- fused QKV + attention + proj --------------------------
// 1024 blocks: blockIdx.x = sequence, blockIdx.y = dir. 512 thr = 8 waves.
// LDS: Xs 64K + Qb(P) 32K + Kb 32K + Vtb 32K = 160 KB.
__global__ __launch_bounds__(512, 2) void k_fused(const short* __restrict__ xu,
                                                  const short* __restrict__ wqkvT0,
                                                  const short* __restrict__ woT0,
                                                  const float* __restrict__ wob0,
                                                  const float* __restrict__ wob1,
                                                  short* __restrict__ accb0,
                                                  short* __restrict__ accb1) {
  __shared__ __align__(16) short Xs[128][256];
  __shared__ __align__(16) short Qb[128][128];   // Q, then P
  __shared__ __align__(16) short Kb[128][128];   // K
  __shared__ __align__(16) short Vtb[128][128];  // V^T

  const int dir = blockIdx.y;
  const short* wqkvT = wqkvT0 + (size_t)dir * 196608;
  const short* woT   = woT0 + (size_t)dir * 65536;
  const float* wob   = dir ? wob1 : wob0;
  short* accb        = dir ? accb1 : accb0;

  const int s = blockIdx.x;
  const int b = s >> 7, pos = s & 127;
  const int tok0 = b * 16384 + (dir ? pos * 128 : pos);
  const int tstep = dir ? 1 : 128;
  const int tid = threadIdx.x;
  const int lane = tid & 63, wid = tid >> 6;
  const int lr = lane & 15, kb = lane >> 4;
  const int ct = wid * 16;                    // wave's chan/token tile base
  const float scale = 0.08838834764831845f;  // 128^-0.5

  // ---- stage Xs: 32 lanes cover one 512 B token row ----
#pragma unroll
  for (int p = 0; p < 8; p++) {
    const int u = p * 512 + tid;
    const int row = u >> 5, ck = (u & 31) * 8;
    bf16x8 v = *(const bf16x8*)(xu + (size_t)(tok0 + row * tstep) * 256 + ck);
    *(bf16x8*)&Xs[row][swz(row, ck)] = v;
  }

  f32x4 accp[16];
#pragma unroll
  for (int i = 0; i < 16; i++) accp[i] = (f32x4){0.f, 0.f, 0.f, 0.f};

  // shfl source lanes for the proj B-operand repack
  const int lsA = lr + (((kb * 2) & 3) << 4);
  const int lsB = lr + (((kb * 2 + 1) & 3) << 4);

  for (int h = 0; h < 2; h++) {
    // weight fragments for this head (L1/L2-hot)
    const short* wqb = wqkvT + (size_t)(h * 128 + ct + lr) * 256 + kb * 8;
    const short* wkb = wqkvT + (size_t)(256 + h * 128 + ct + lr) * 256 + kb * 8;
    const short* wvb = wqkvT + (size_t)(512 + h * 128 + ct + lr) * 256 + kb * 8;
    bf16x8 wq[8], wk[8], wv[8];
#pragma unroll
    for (int ks = 0; ks < 8; ks++) {
      wq[ks] = *(const bf16x8*)(wqb + ks * 32);
      wk[ks] = *(const bf16x8*)(wkb + ks * 32);
      wv[ks] = *(const bf16x8*)(wvb + ks * 32);
    }

    __syncthreads();  // A: Xs staged (h=0) / prev head's PV+S LDS reads done

    // ---- merged Q/K/V production (chan-owned slice ct..ct+15) ----
#pragma unroll
    for (int nt = 0; nt < 8; nt++) {
      const int xrow = nt * 16 + lr;
      f32x4 dq = (f32x4){0.f, 0.f, 0.f, 0.f};
      f32x4 dk = (f32x4){0.f, 0.f, 0.f, 0.f};
      f32x4 dv = (f32x4){0.f, 0.f, 0.f, 0.f};
#pragma unroll
      for (int ks = 0; ks < 8; ks++) {
        bf16x8 xf = *(const bf16x8*)&Xs[xrow][swz(xrow, kb * 8 + ks * 32)];
        dq = MFMA16(wq[ks], xf, dq);   // D[chan][token]
        dk = MFMA16(wk[ks], xf, dk);   // D[chan][token]
        dv = MFMA16(xf, wv[ks], dv);   // swapped: D[token][chan]
      }
      const int trow = nt * 16 + lr, cc = ct + kb * 4;
      bf16x4 pq = {f2bf(dq[0]), f2bf(dq[1]), f2bf(dq[2]), f2bf(dq[3])};
      bf16x4 pk = {f2bf(dk[0]), f2bf(dk[1]), f2bf(dk[2]), f2bf(dk[3])};
      *(bf16x4*)&Qb[trow][swz(trow, cc)] = pq;
      *(bf16x4*)&Kb[trow][swz(trow, cc)] = pk;
      const int vrow = ct + lr;
      bf16x4 pv = {f2bf(dv[0]), f2bf(dv[1]), f2bf(dv[2]), f2bf(dv[3])};
      *(bf16x4*)&Vtb[vrow][swz(vrow, nt * 16 + kb * 4)] = pv;
    }

    __syncthreads();  // B: Q/K/Vt visible to all waves

    // ---- S^T = K Q^T : lane owns q-token ct+lr ----
    f32x4 s8[8];
#pragma unroll
    for (int i = 0; i < 8; i++) s8[i] = (f32x4){0.f, 0.f, 0.f, 0.f};
    const int qrow = ct + lr;
#pragma unroll
    for (int ks = 0; ks < 4; ks++) {
      bf16x8 aq = *(const bf16x8*)&Qb[qrow][swz(qrow, kb * 8 + ks * 32)];
#pragma unroll
      for (int nj = 0; nj < 8; nj++) {
        const int krow = nj * 16 + lr;
        bf16x8 bk = *(const bf16x8*)&Kb[krow][swz(krow, kb * 8 + ks * 32)];
        s8[nj] = MFMA16(bk, aq, s8[nj]);   // D[k-token][q-token]
      }
    }
    // ---- per-lane softmax (xor 16, 32); P overwrites own Qb row ----
    {
      float m = s8[0][0];
#pragma unroll
      for (int nj = 0; nj < 8; nj++)
#pragma unroll
        for (int r = 0; r < 4; r++) m = fmaxf(m, s8[nj][r]);
      m = fmaxf(m, __shfl_xor(m, 16));
      m = fmaxf(m, __shfl_xor(m, 32));
      float sum = 0.f;
#pragma unroll
      for (int nj = 0; nj < 8; nj++)
#pragma unroll
        for (int r = 0; r < 4; r++) {
          s8[nj][r] = __expf((s8[nj][r] - m) * scale);
          sum += s8[nj][r];
        }
      sum += __shfl_xor(sum, 16);
      sum += __shfl_xor(sum, 32);
      const float inv = 1.f / sum;
#pragma unroll
      for (int nj = 0; nj < 8; nj++) {
        bf16x4 pp = {f2bf(s8[nj][0] * inv), f2bf(s8[nj][1] * inv),
                     f2bf(s8[nj][2] * inv), f2bf(s8[nj][3] * inv)};
        *(bf16x4*)&Qb[qrow][swz(qrow, nj * 16 + kb * 4)] = pp;
      }
    }

    // ---- O = P V : own q-token; result stays in registers ----
    f32x4 o8[8];
#pragma unroll
    for (int i = 0; i < 8; i++) o8[i] = (f32x4){0.f, 0.f, 0.f, 0.f};
#pragma unroll
    for (int ks = 0; ks < 4; ks++) {
      bf16x8 bp = *(const bf16x8*)&Qb[qrow][swz(qrow, kb * 8 + ks * 32)];
#pragma unroll
      for (int mi = 0; mi < 8; mi++) {
        const int vrow = mi * 16 + lr;
        bf16x8 av = *(const bf16x8*)&Vtb[vrow][swz(vrow, kb * 8 + ks * 32)];
        o8[mi] = MFMA16(av, bp, o8[mi]);   // D[chan][q-token]
      }
    }

    // ---- repack O (D-layout) -> proj B-operand (in-register, shfl) ----
    // producer lane (kb_p, lr) holds chans mi*16 + kb_p*4 + r of q-token ct+lr.
    // consumer lane (ck, lr) frag[ks] needs chans 32ks + 8ck + u.
    unsigned po[8][2];
#pragma unroll
    for (int mi = 0; mi < 8; mi++) {
      po[mi][0] = pk2(o8[mi][0], o8[mi][1]);
      po[mi][1] = pk2(o8[mi][2], o8[mi][3]);
    }
    bf16x8 bfr[4];
#pragma unroll
    for (int mi = 0; mi < 8; mi++) {
      unsigned loA = (unsigned)__shfl((int)po[mi][0], lsA, 64);
      unsigned hiA = (unsigned)__shfl((int)po[mi][1], lsA, 64);
      unsigned loB = (unsigned)__shfl((int)po[mi][0], lsB, 64);
      unsigned hiB = (unsigned)__shfl((int)po[mi][1], lsB, 64);
      if ((mi & 1) == (kb >> 1)) {
        union { u32x4 u; bf16x8 b; } cv;
        cv.u = (u32x4){loA, hiA, loB, hiB};
        bfr[mi >> 1] = cv.b;
      }
    }

    // ---- proj: own 16 tokens x all 256 out-chans, accumulate in regs ----
#pragma unroll
    for (int t = 0; t < 16; t++) {
      const short* wp = woT + (size_t)(t * 16 + lr) * 256 + h * 128 + kb * 8;
#pragma unroll
      for (int ks = 0; ks < 4; ks++) {
        bf16x8 w = *(const bf16x8*)(wp + ks * 32);
        accp[t] = MFMA16(w, bfr[ks], accp[t]);   // D[outc][token]
      }
    }
  }

  // ---- accb write: token = ct+lr (own), outc = t*16 + kb*4 + r ----
  const int token = tok0 + (ct + lr) * tstep;
#pragma unroll
  for (int t = 0; t < 16; t++) {
    const int outc = t * 16 + kb * 4;
    bf16x4 pv = {f2bf(accp[t][0] + wob[outc]),
                 f2bf(accp[t][1] + wob[outc + 1]),
                 f2bf(accp[t][2] + wob[outc + 2]),
                 f2bf(accp[t][3] + wob[outc + 3])};
    *(bf16x4*)(accb + (size_t)token * 256 + outc) = pv;
  }
}

// ---------------- conv1x1: [relu(a0+a1)|xu|res] @ convT^T -> relu -> ytmp ---
__global__ __launch_bounds__(256) void k_gemm_conv(const short* __restrict__ accb0,
                                                   const short* __restrict__ accb1,
                                                   const short* __restrict__ xu,
                                                   const float* __restrict__ res,
                                                   const short* __restrict__ Bt,
                                                   float* __restrict__ ytmp) {
  const int tid = threadIdx.x;
  const int lane = tid & 63, wid = tid >> 6;
  const int lr = lane & 15, kb = lane >> 4;
  const int wr = wid >> 1, wc = wid & 1;
  const int m0 = blockIdx.y * 128;
  f32x4 acc[4][4];
#pragma unroll
  for (int i = 0; i < 4; i++)
#pragma unroll
    for (int j = 0; j < 4; j++) acc[i][j] = (f32x4){0.f, 0.f, 0.f, 0.f};
  const short* arow0 = accb0 + (size_t)(m0 + wr * 64 + lr) * 256 + kb * 8;
  const short* arow1 = accb1 + (size_t)(m0 + wr * 64 + lr) * 256 + kb * 8;
  const short* arow2 = xu + (size_t)(m0 + wr * 64 + lr) * 256 + kb * 8;
  const short* brow = Bt + (size_t)(wc * 64 + lr) * 640 + kb * 8;
#pragma unroll
  for (int ks = 0; ks < 8; ks++) {
    bf16x8 a[4], b[4];
#pragma unroll
    for (int mi = 0; mi < 4; mi++) {
      bf16x8 t0 = *(const bf16x8*)(arow0 + (size_t)mi * 16 * 256 + ks * 32);
      bf16x8 t1 = *(const bf16x8*)(arow1 + (size_t)mi * 16 * 256 + ks * 32);
      bf16x8 tv;
#pragma unroll
      for (int u = 0; u < 8; u++) {
        float sv = bf2f(t0[u]) + bf2f(t1[u]);
        tv[u] = f2bf(fmaxf(sv, 0.f));
      }
      a[mi] = tv;
    }
#pragma unroll
    for (int nj = 0; nj < 4; nj++)
      b[nj] = *(const bf16x8*)(brow + (size_t)nj * 16 * 640 + ks * 32);
#pragma unroll
    for (int mi = 0; mi < 4; mi++)
#pragma unroll
      for (int nj = 0; nj < 4; nj++)
        acc[mi][nj] = MFMA16(a[mi], b[nj], acc[mi][nj]);
  }
#pragma unroll
  for (int ks = 8; ks < 16; ks++) {
    bf16x8 a[4], b[4];
#pragma unroll
    for (int mi = 0; mi < 4; mi++)
      a[mi] = *(const bf16x8*)(arow2 + (size_t)mi * 16 * 256 + (ks - 8) * 32);
#pragma unroll
    for (int nj = 0; nj < 4; nj++)
      b[nj] = *(const bf16x8*)(brow + (size_t)nj * 16 * 640 + ks * 32);
#pragma unroll
    for (int mi = 0; mi < 4; mi++)
#pragma unroll
      for (int nj = 0; nj < 4; nj++)
        acc[mi][nj] = MFMA16(a[mi], b[nj], acc[mi][nj]);
  }
  const int bC = (m0 >> 14) * 128;
  const int hh = (m0 >> 7) & 127;
#pragma unroll
  for (int ks = 16; ks < 20; ks++) {
    const int e0 = (ks - 16) * 32 + kb * 8;
    bf16x8 a[4], b[4];
#pragma unroll
    for (int mi = 0; mi < 4; mi++) {
      const int wl = wr * 64 + mi * 16 + lr;
      const float* rp = res + ((size_t)(bC + e0) * 128 + hh) * 128 + wl;
      bf16x8 tv;
#pragma unroll
      for (int u = 0; u < 8; u++) tv[u] = f2bf(rp[(size_t)u * 16384]);
      a[mi] = tv;
    }
#pragma unroll
    for (int nj = 0; nj < 4; nj++)
      b[nj] = *(const bf16x8*)(brow + (size_t)nj * 16 * 640 + ks * 32);
#pragma unroll
    for (int mi = 0; mi < 4; mi++)
#pragma unroll
      for (int nj = 0; nj < 4; nj++)
        acc[mi][nj] = MFMA16(a[mi], b[nj], acc[mi][nj]);
  }
#pragma unroll
  for (int mi = 0; mi < 4; mi++) {
    const int rbase = m0 + wr * 64 + mi * 16 + kb * 4;
#pragma unroll
    for (int nj = 0; nj < 4; nj++) {
      const int c = wc * 64 + nj * 16 + lr;
#pragma unroll
      for (int r = 0; r < 4; r++)
        ytmp[(size_t)(rbase + r) * 128 + c] = fmaxf(acc[mi][nj][r], 0.f);
    }
  }
}

// ---------------- BN stats pass 1 ----------------
__global__ __launch_bounds__(256) void k_bnstats1(const float* __restrict__ y,
                                                  float* __restrict__ partial) {
  const int blk = blockIdx.x, tid = threadIdx.x;
  const int ch = tid & 127, sub = tid >> 7;
  float s = 0.f, s2 = 0.f;
  const float* p = y + (size_t)(blk * 512 + sub) * 128 + ch;
  for (int i = 0; i < 256; i++) {
    float v = p[(size_t)i * 256];
    s += v; s2 += v * v;
  }
  __shared__ float rs[2][128], rs2[2][128];
  rs[sub][ch] = s; rs2[sub][ch] = s2;
  __syncthreads();
  if (tid < 128) {
    partial[(size_t)(blk * 128 + tid) * 2]     = rs[0][tid] + rs[1][tid];
    partial[(size_t)(blk * 128 + tid) * 2 + 1] = rs2[0][tid] + rs2[1][tid];
  }
}

// ---------------- BN stats pass 2 ----------------
__global__ __launch_bounds__(128) void k_bnstats2(const float* __restrict__ partial,
                                                  float* __restrict__ stats) {
  const int ch = threadIdx.x;
  float s = 0.f, s2 = 0.f;
  for (int i = 0; i < 128; i++) {
    s  += partial[(size_t)(i * 128 + ch) * 2];
    s2 += partial[(size_t)(i * 128 + ch) * 2 + 1];
  }
  const float mu = s * (1.f / 65536.f);
  const float var = s2 * (1.f / 65536.f) - mu * mu;
  stats[ch * 2] = mu;
  stats[ch * 2 + 1] = rsqrtf(var + 1e-5f);
}

// ---------------- BN apply + transpose to (B,E,H,W) ----------------
__global__ __launch_bounds__(256) void k_bnout(const float* __restrict__ y,
                                               const float* __restrict__ stats,
                                               const float* __restrict__ gamma,
                                               const float* __restrict__ beta,
                                               float* __restrict__ out) {
  const int bh = blockIdx.x;
  const int b = bh >> 7, h = bh & 127;
  const int w = threadIdx.x & 127, eh = threadIdx.x >> 7;
  const float* yp = y + (size_t)(bh * 128 + w) * 128;
  for (int e2 = 0; e2 < 64; e2++) {
    const int e = e2 * 2 + eh;
    const float mu = stats[e * 2], rstd = stats[e * 2 + 1];
    const float v = yp[e];
    out[((size_t)(b * 128 + e) << 14) + h * 128 + w] =
        (v - mu) * rstd * gamma[e] + beta[e];
  }
}

// ---------------- launcher ----------------
extern "C" void kernel_launch(void* const* d_in, const int* in_sizes, int n_in,
                              void* d_out, int out_size, void* d_ws, size_t ws_size,
                              hipStream_t stream) {
  const float* x      = (const float*)d_in[0];
  const float* res    = (const float*)d_in[1];
  const float* wq_h   = (const float*)d_in[2];
  const float* wkv_h  = (const float*)d_in[3];
  const float* wo_h   = (const float*)d_in[4];
  const float* wob_h  = (const float*)d_in[5];
  const float* wq_w   = (const float*)d_in[6];
  const float* wkv_w  = (const float*)d_in[7];
  const float* wo_w   = (const float*)d_in[8];
  const float* wob_w  = (const float*)d_in[9];
  const float* conv_w = (const float*)d_in[10];
  const float* gamma  = (const float*)d_in[11];
  const float* beta   = (const float*)d_in[12];

  char* ws = (char*)d_ws;
  short* wqkvT[2] = {(short*)(ws + 0), (short*)(ws + 393216)};
  short* woT[2]   = {(short*)(ws + 786432), (short*)(ws + 917504)};
  short* convT    = (short*)(ws + 1048576);
  short* xu       = (short*)(ws + 1245184);
  float* ytmp     = (float*)(ws + 34799616);
  float* partial  = (float*)(ws + 68354048);
  float* stats    = (float*)(ws + 68485120);
  short* accb1    = (short*)(ws + 68486144);
  short* accb0    = (short*)d_out;             // dir-0 axial output in d_out
  float* out      = (float*)d_out;

  if (ws_size < 102040576ull)
    fprintf(stderr, "kernel_launch: ws_size %zu too small\n", ws_size);

  // fused weight prep: starts 0,64,192,256,384,448,512; total 592 tiles
  WtAll P;
  P.src[0] = wq_h;  P.dst[0] = wqkvT[0];          P.K[0] = 256; P.N[0] = 256; P.tile0[0] = 0;
  P.src[1] = wkv_h; P.dst[1] = wqkvT[0] + 65536;  P.K[1] = 256; P.N[1] = 512; P.tile0[1] = 64;
  P.src[2] = wq_w;  P.dst[2] = wqkvT[1];          P.K[2] = 256; P.N[2] = 256; P.tile0[2] = 192;
  P.src[3] = wkv_w; P.dst[3] = wqkvT[1] + 65536;  P.K[3] = 256; P.N[3] = 512; P.tile0[3] = 256;
  P.src[4] = wo_h;  P.dst[4] = woT[0];            P.K[4] = 256; P.N[4] = 256; P.tile0[4] = 384;
  P.src[5] = wo_w;  P.dst[5] = woT[1];            P.K[5] = 256; P.N[5] = 256; P.tile0[5] = 448;
  P.src[6] = conv_w;P.dst[6] = convT;             P.K[6] = 640; P.N[6] = 128; P.tile0[6] = 512;
  k_wt_all<<<592, 256, 0, stream>>>(P);

  k_upsample<<<dim3(512, 4), 256, 0, stream>>>(x, xu);

  k_fused<<<dim3(512, 2), 512, 0, stream>>>(xu, wqkvT[0], woT[0],
                                            wob_h, wob_w, accb0, accb1);

  k_gemm_conv<<<dim3(1, 512), 256, 0, stream>>>(accb0, accb1, xu, res, convT, ytmp);
  k_bnstats1<<<128, 256, 0, stream>>>(ytmp, partial);
  k_bnstats2<<<1, 128, 0, stream>>>(partial, stats);
  k_bnout<<<512, 256, 0, stream>>>(ytmp, stats, gamma, beta, out);
}

// Round 8
// 333.563 us; speedup vs baseline: 1.0702x; 1.0702x over previous
//
#include <hip/hip_runtime.h>
#include <hip/hip_bf16.h>
#include <cstdio>

// BlockAxialUp on MI355X, round 8:
//  - k_fused: 1024 threads (16 waves, 4 waves/SIMD) with per-phase work split:
//      production token-halved, S key-split + (m,l) online-merge via global
//      scratch, PV chan-split (no partial-O), proj outc-split.
//  - round-7 shfl repack reverted (ds_bpermute cost); proj reads O from LDS.
//  - conv: fused BN-stats partials (exact f32), bf16 ytmp; bnout coalesced.
//
// ws layout (bytes):
//   0         wqkvT_h bf16 [768][256] (q 0:256, k 256:512, v 512:768)
//   393216    wqkvT_w
//   786432    woT_h  bf16 [256][256]
//   917504    woT_w
//   1048576   convT  bf16 [128][640]
//   1245184   xu     bf16 [65536][256]
//   34799616  ytmp   bf16 [65536][128]
//   51576832  partial f32 [512][128][2]
//   52101120  stats  f32  [128][2]
//   52102144  accb1  bf16 [65536][256]
//   85656576  sm     f32  [1024 blocks][512]   (softmax (m,l) exchange)
//   -> end 87753728
// accb0 (dir-0) lives in d_out; final f32 output overwrites it.

typedef short bf16x8 __attribute__((ext_vector_type(8)));
typedef short bf16x4 __attribute__((ext_vector_type(4)));
typedef float f32x4 __attribute__((ext_vector_type(4)));

#define MFMA16(a, b, c) __builtin_amdgcn_mfma_f32_16x16x32_bf16((a), (b), (c), 0, 0, 0)

__device__ __forceinline__ short f2bf(float v) {
  __hip_bfloat16 h = __float2bfloat16(v);
  union { __hip_bfloat16 h; short s; } u; u.h = h; return u.s;
}
__device__ __forceinline__ float bf2f(short s) {
  return __uint_as_float(((unsigned int)(unsigned short)s) << 16);
}
// XOR swizzle, granule = 8 shorts (16 B); flips col bits 3-5 only.
__device__ __forceinline__ int swz(int row, int col) {
  return col ^ ((row & 7) << 3);
}

// ---------------- fused weight prep: dst[n][k] = bf16(src[k][n]) ------------
struct WtAll {
  const float* src[7];
  short* dst[7];
  int K[7], N[7], tile0[7];
};

__global__ __launch_bounds__(256) void k_wt_all(WtAll P) {
  const int bid = blockIdx.x;
  int i = 0;
#pragma unroll
  for (int j = 1; j < 7; j++) if (bid >= P.tile0[j]) i = j;
  const float* src = P.src[i];
  short* dst = P.dst[i];
  const int K = P.K[i], N = P.N[i];
  const int local = bid - P.tile0[i];
  const int ktiles = K >> 5;
  const int nt = local / ktiles, kt = local - nt * ktiles;
  const int k0 = kt * 32, n0 = nt * 32;
  __shared__ float tile[32][33];
  const int tx = threadIdx.x & 31, ty = threadIdx.x >> 5;
#pragma unroll
  for (int r = 0; r < 4; r++)
    tile[ty + r * 8][tx] = src[(size_t)(k0 + ty + r * 8) * N + n0 + tx];
  __syncthreads();
#pragma unroll
  for (int r = 0; r < 4; r++)
    dst[(size_t)(n0 + ty + r * 8) * K + k0 + tx] = f2bf(tile[tx][ty + r * 8]);
}

// ---------------- upsample 2x bilinear align_corners --------------------
__global__ __launch_bounds__(256) void k_upsample(const float* __restrict__ x,
                                                  short* __restrict__ xu) {
  __shared__ float ldsV[64][65];
  const int bh = blockIdx.x, z = blockIdx.y;
  const int b = bh >> 7, h = bh & 127;
  const float chf = h * (63.0f / 127.0f);
  int i0 = (int)chf; if (i0 > 62) i0 = 62;
  const float wh = chf - (float)i0;
  const int t = threadIdx.x;
  const int cbase = z * 64;
  const float* xb = x + ((size_t)(b * 256 + cbase) * 64 + i0) * 64;
#pragma unroll
  for (int p = 0; p < 16; p++) {
    const int li = p * 256 + t;
    const int c = li >> 6, w = li & 63;
    const float* px = xb + (size_t)c * 4096 + w;
    const float v0 = px[0], v1 = px[64];
    ldsV[c][w] = v0 * (1.f - wh) + v1 * wh;
  }
  __syncthreads();
  const int cg = t & 7, wi = t >> 3;
  short* xout = xu + (size_t)(bh * 128) * 256 + cbase + cg * 8;
#pragma unroll
  for (int p = 0; p < 4; p++) {
    const int w = p * 32 + wi;
    const float cwf = w * (63.0f / 127.0f);
    int j0 = (int)cwf; if (j0 > 62) j0 = 62;
    const float ww = cwf - (float)j0;
    bf16x8 o;
#pragma unroll
    for (int u = 0; u < 8; u++) {
      const float v0 = ldsV[cg * 8 + u][j0], v1 = ldsV[cg * 8 + u][j0 + 1];
      o[u] = f2bf(v0 * (1.f - ww) + v1 * ww);
    }
    *(bf16x8*)(xout + (size_t)w * 256) = o;
  }
}

// ---------------- fused QKV + attention + proj --------------------------
// grid (512, 2): blockIdx.x = sequence, blockIdx.y = dir.
// 1024 thr = 16 waves: grp = wid>>3 (token/key/chan half), sw = wid&7.
// LDS: Xs 64K + Qb(P) 32K + Kb(O) 32K + Vtb 32K = 160 KB -> 1 blk/CU, 4 w/SIMD.
__global__ __launch_bounds__(1024) void k_fused(const short* __restrict__ xu,
                                                const short* __restrict__ wqkvT0,
                                                const short* __restrict__ woT0,
                                                const float* __restrict__ wob0,
                                                const float* __restrict__ wob1,
                                                short* __restrict__ accb0,
                                                short* __restrict__ accb1,
                                                float* __restrict__ smg) {
  __shared__ __align__(16) short Xs[128][256];
  __shared__ __align__(16) short Qb[128][128];   // Q, then P
  __shared__ __align__(16) short Kb[128][128];   // K, then O
  __shared__ __align__(16) short Vtb[128][128];  // V^T

  const int dir = blockIdx.y;
  const short* wqkvT = wqkvT0 + (size_t)dir * 196608;
  const short* woT   = woT0 + (size_t)dir * 65536;
  const float* wob   = dir ? wob1 : wob0;
  short* accb        = dir ? accb1 : accb0;
  float* sm = smg + (size_t)(blockIdx.y * 512 + blockIdx.x) * 512;  // [2][128][2] f32

  const int s = blockIdx.x;
  const int b = s >> 7, pos = s & 127;
  const int tok0 = b * 16384 + (dir ? pos * 128 : pos);
  const int tstep = dir ? 1 : 128;
  const int tid = threadIdx.x;
  const int lane = tid & 63, wid = tid >> 6;
  const int lr = lane & 15, kb = lane >> 4;
  const int grp = wid >> 3, sw = wid & 7;
  const int ct = sw * 16;                     // chan tile (prod) / token tile (attn)
  const float scale = 0.08838834764831845f;  // 128^-0.5

  // ---- stage Xs: 32 lanes cover one 512 B token row ----
#pragma unroll
  for (int p = 0; p < 4; p++) {
    const int u = p * 1024 + tid;
    const int row = u >> 5, ck = (u & 31) * 8;
    bf16x8 v = *(const bf16x8*)(xu + (size_t)(tok0 + row * tstep) * 256 + ck);
    *(bf16x8*)&Xs[row][swz(row, ck)] = v;
  }

  f32x4 accp[8];
#pragma unroll
  for (int i = 0; i < 8; i++) accp[i] = (f32x4){0.f, 0.f, 0.f, 0.f};

  for (int h = 0; h < 2; h++) {
    __syncthreads();  // A: Xs staged (h=0) / prev head's proj reads of Kb done

    // ---- production: chans ct..ct+15, tokens grp*64..grp*64+63 ----
    {
      const short* wqb = wqkvT + (size_t)(h * 128 + ct + lr) * 256 + kb * 8;
      const short* wkb = wqkvT + (size_t)(256 + h * 128 + ct + lr) * 256 + kb * 8;
      const short* wvb = wqkvT + (size_t)(512 + h * 128 + ct + lr) * 256 + kb * 8;
      f32x4 dq[4], dk[4], dv[4];
#pragma unroll
      for (int i = 0; i < 4; i++) {
        dq[i] = (f32x4){0.f, 0.f, 0.f, 0.f};
        dk[i] = (f32x4){0.f, 0.f, 0.f, 0.f};
        dv[i] = (f32x4){0.f, 0.f, 0.f, 0.f};
      }
#pragma unroll
      for (int ks = 0; ks < 8; ks++) {
        bf16x8 fq = *(const bf16x8*)(wqb + ks * 32);
        bf16x8 fk = *(const bf16x8*)(wkb + ks * 32);
        bf16x8 fv = *(const bf16x8*)(wvb + ks * 32);
#pragma unroll
        for (int i = 0; i < 4; i++) {
          const int xrow = (grp * 4 + i) * 16 + lr;
          bf16x8 xf = *(const bf16x8*)&Xs[xrow][swz(xrow, kb * 8 + ks * 32)];
          dq[i] = MFMA16(fq, xf, dq[i]);   // D[chan][token]
          dk[i] = MFMA16(fk, xf, dk[i]);   // D[chan][token]
          dv[i] = MFMA16(xf, fv, dv[i]);   // D[token][chan]
        }
      }
#pragma unroll
      for (int i = 0; i < 4; i++) {
        const int nt = grp * 4 + i;
        const int trow = nt * 16 + lr, cc = ct + kb * 4;
        bf16x4 pq = {f2bf(dq[i][0]), f2bf(dq[i][1]), f2bf(dq[i][2]), f2bf(dq[i][3])};
        bf16x4 pk = {f2bf(dk[i][0]), f2bf(dk[i][1]), f2bf(dk[i][2]), f2bf(dk[i][3])};
        *(bf16x4*)&Qb[trow][swz(trow, cc)] = pq;
        *(bf16x4*)&Kb[trow][swz(trow, cc)] = pk;
        const int vrow = ct + lr;
        bf16x4 pv = {f2bf(dv[i][0]), f2bf(dv[i][1]), f2bf(dv[i][2]), f2bf(dv[i][3])};
        *(bf16x4*)&Vtb[vrow][swz(vrow, nt * 16 + kb * 4)] = pv;
      }
    }

    __syncthreads();  // B: Q/K/Vt visible to all waves

    // ---- S^T = K Q^T : q-tokens ct+lr, keys grp*64..+63 (split) ----
    f32x4 s8[4];
#pragma unroll
    for (int i = 0; i < 4; i++) s8[i] = (f32x4){0.f, 0.f, 0.f, 0.f};
    const int qrow = ct + lr;
#pragma unroll
    for (int ks = 0; ks < 4; ks++) {
      bf16x8 aq = *(const bf16x8*)&Qb[qrow][swz(qrow, kb * 8 + ks * 32)];
#pragma unroll
      for (int j = 0; j < 4; j++) {
        const int krow = (grp * 4 + j) * 16 + lr;
        bf16x8 bk = *(const bf16x8*)&Kb[krow][swz(krow, kb * 8 + ks * 32)];
        s8[j] = MFMA16(bk, aq, s8[j]);   // D[k-token][q-token]
      }
    }
    // partial softmax over own 64 keys (in-lane 16 + xor 16,32 over kb)
    float m = s8[0][0];
#pragma unroll
    for (int j = 0; j < 4; j++)
#pragma unroll
      for (int r = 0; r < 4; r++) m = fmaxf(m, s8[j][r]);
    m = fmaxf(m, __shfl_xor(m, 16));
    m = fmaxf(m, __shfl_xor(m, 32));
    float l = 0.f;
#pragma unroll
    for (int j = 0; j < 4; j++)
#pragma unroll
      for (int r = 0; r < 4; r++) l += __expf((s8[j][r] - m) * scale);
    l += __shfl_xor(l, 16);
    l += __shfl_xor(l, 32);
    if (kb == 0) {
      sm[grp * 256 + (ct + lr) * 2]     = m;
      sm[grp * 256 + (ct + lr) * 2 + 1] = l;
    }

    __syncthreads();  // C: SM written; all S reads of Qb/Kb done

    // merge (m,l) with other grp; compute P for own keys; write into Qb
    {
      const int og = 1 - grp;
      const float mo = sm[og * 256 + (ct + lr) * 2];
      const float lo = sm[og * 256 + (ct + lr) * 2 + 1];
      const float M = fmaxf(m, mo);
      const float L = l * __expf((m - M) * scale) + lo * __expf((mo - M) * scale);
      const float inv = 1.f / L;
#pragma unroll
      for (int j = 0; j < 4; j++) {
        bf16x4 pp = {f2bf(__expf((s8[j][0] - M) * scale) * inv),
                     f2bf(__expf((s8[j][1] - M) * scale) * inv),
                     f2bf(__expf((s8[j][2] - M) * scale) * inv),
                     f2bf(__expf((s8[j][3] - M) * scale) * inv)};
        *(bf16x4*)&Qb[qrow][swz(qrow, (grp * 4 + j) * 16 + kb * 4)] = pp;
      }
    }

    __syncthreads();  // D: full P visible

    // ---- O = P V : own q-tokens, chans grp*64..+63 (split); final bf16 ----
    f32x4 o8[4];
#pragma unroll
    for (int i = 0; i < 4; i++) o8[i] = (f32x4){0.f, 0.f, 0.f, 0.f};
#pragma unroll
    for (int ks = 0; ks < 4; ks++) {
      bf16x8 bp = *(const bf16x8*)&Qb[qrow][swz(qrow, kb * 8 + ks * 32)];
#pragma unroll
      for (int mi = 0; mi < 4; mi++) {
        const int vrow = (grp * 4 + mi) * 16 + lr;
        bf16x8 av = *(const bf16x8*)&Vtb[vrow][swz(vrow, kb * 8 + ks * 32)];
        o8[mi] = MFMA16(av, bp, o8[mi]);   // D[chan][q-token]
      }
    }
#pragma unroll
    for (int mi = 0; mi < 4; mi++) {
      const int cc = (grp * 4 + mi) * 16 + kb * 4;
      bf16x4 po = {f2bf(o8[mi][0]), f2bf(o8[mi][1]), f2bf(o8[mi][2]), f2bf(o8[mi][3])};
      *(bf16x4*)&Kb[qrow][swz(qrow, cc)] = po;
    }

    __syncthreads();  // E: O complete

    // ---- proj: own 16 out-chans (wid*16..+15), all tokens ----
    {
      const short* wp = woT + (size_t)(wid * 16 + lr) * 256 + h * 128 + kb * 8;
      bf16x8 w4[4];
#pragma unroll
      for (int ks = 0; ks < 4; ks++) w4[ks] = *(const bf16x8*)(wp + ks * 32);
#pragma unroll
      for (int nt = 0; nt < 8; nt++) {
        const int trow = nt * 16 + lr;
#pragma unroll
        for (int ks = 0; ks < 4; ks++) {
          bf16x8 bo = *(const bf16x8*)&Kb[trow][swz(trow, kb * 8 + ks * 32)];
          accp[nt] = MFMA16(w4[ks], bo, accp[nt]);   // D[outc][token]
        }
      }
    }
  }

  // ---- accb write: token = nt*16+lr, outc = wid*16 + kb*4 + r ----
  const int outc = wid * 16 + kb * 4;
  const float b0 = wob[outc], b1 = wob[outc + 1];
  const float b2 = wob[outc + 2], b3 = wob[outc + 3];
#pragma unroll
  for (int nt = 0; nt < 8; nt++) {
    const int token = tok0 + (nt * 16 + lr) * tstep;
    bf16x4 pv = {f2bf(accp[nt][0] + b0), f2bf(accp[nt][1] + b1),
                 f2bf(accp[nt][2] + b2), f2bf(accp[nt][3] + b3)};
    *(bf16x4*)(accb + (size_t)token * 256 + outc) = pv;
  }
}

// ---- conv1x1: [relu(a0+a1)|xu|res] @ convT^T -> relu -> ytmp(bf16) + BN partials
__global__ __launch_bounds__(256) void k_gemm_conv(const short* __restrict__ accb0,
                                                   const short* __restrict__ accb1,
                                                   const short* __restrict__ xu,
                                                   const float* __restrict__ res,
                                                   const short* __restrict__ Bt,
                                                   short* __restrict__ ytmp,
                                                   float* __restrict__ partial) {
  __shared__ float redS[2][128], redS2[2][128];
  const int tid = threadIdx.x;
  const int lane = tid & 63, wid = tid >> 6;
  const int lr = lane & 15, kb = lane >> 4;
  const int wr = wid >> 1, wc = wid & 1;
  const int m0 = blockIdx.y * 128;
  f32x4 acc[4][4];
#pragma unroll
  for (int i = 0; i < 4; i++)
#pragma unroll
    for (int j = 0; j < 4; j++) acc[i][j] = (f32x4){0.f, 0.f, 0.f, 0.f};
  const short* arow0 = accb0 + (size_t)(m0 + wr * 64 + lr) * 256 + kb * 8;
  const short* arow1 = accb1 + (size_t)(m0 + wr * 64 + lr) * 256 + kb * 8;
  const short* arow2 = xu + (size_t)(m0 + wr * 64 + lr) * 256 + kb * 8;
  const short* brow = Bt + (size_t)(wc * 64 + lr) * 640 + kb * 8;
#pragma unroll
  for (int ks = 0; ks < 8; ks++) {
    bf16x8 a[4], b[4];
#pragma unroll
    for (int mi = 0; mi < 4; mi++) {
      bf16x8 t0 = *(const bf16x8*)(arow0 + (size_t)mi * 16 * 256 + ks * 32);
      bf16x8 t1 = *(const bf16x8*)(arow1 + (size_t)mi * 16 * 256 + ks * 32);
      bf16x8 tv;
#pragma unroll
      for (int u = 0; u < 8; u++) {
        float sv = bf2f(t0[u]) + bf2f(t1[u]);
        tv[u] = f2bf(fmaxf(sv, 0.f));
      }
      a[mi] = tv;
    }
#pragma unroll
    for (int nj = 0; nj < 4; nj++)
      b[nj] = *(const bf16x8*)(brow + (size_t)nj * 16 * 640 + ks * 32);
#pragma unroll
    for (int mi = 0; mi < 4; mi++)
#pragma unroll
      for (int nj = 0; nj < 4; nj++)
        acc[mi][nj] = MFMA16(a[mi], b[nj], acc[mi][nj]);
  }
#pragma unroll
  for (int ks = 8; ks < 16; ks++) {
    bf16x8 a[4], b[4];
#pragma unroll
    for (int mi = 0; mi < 4; mi++)
      a[mi] = *(const bf16x8*)(arow2 + (size_t)mi * 16 * 256 + (ks - 8) * 32);
#pragma unroll
    for (int nj = 0; nj < 4; nj++)
      b[nj] = *(const bf16x8*)(brow + (size_t)nj * 16 * 640 + ks * 32);
#pragma unroll
    for (int mi = 0; mi < 4; mi++)
#pragma unroll
      for (int nj = 0; nj < 4; nj++)
        acc[mi][nj] = MFMA16(a[mi], b[nj], acc[mi][nj]);
  }
  const int bC = (m0 >> 14) * 128;
  const int hh = (m0 >> 7) & 127;
#pragma unroll
  for (int ks = 16; ks < 20; ks++) {
    const int e0 = (ks - 16) * 32 + kb * 8;
    bf16x8 a[4], b[4];
#pragma unroll
    for (int mi = 0; mi < 4; mi++) {
      const int wl = wr * 64 + mi * 16 + lr;
      const float* rp = res + ((size_t)(bC + e0) * 128 + hh) * 128 + wl;
      bf16x8 tv;
#pragma unroll
      for (int u = 0; u < 8; u++) tv[u] = f2bf(rp[(size_t)u * 16384]);
      a[mi] = tv;
    }
#pragma unroll
    for (int nj = 0; nj < 4; nj++)
      b[nj] = *(const bf16x8*)(brow + (size_t)nj * 16 * 640 + ks * 32);
#pragma unroll
    for (int mi = 0; mi < 4; mi++)
#pragma unroll
      for (int nj = 0; nj < 4; nj++)
        acc[mi][nj] = MFMA16(a[mi], b[nj], acc[mi][nj]);
  }
  // epilogue: relu -> bf16 ytmp + per-channel partial sums (exact f32)
#pragma unroll
  for (int nj = 0; nj < 4; nj++) {
    float s = 0.f, s2 = 0.f;
    const int c = wc * 64 + nj * 16 + lr;
#pragma unroll
    for (int mi = 0; mi < 4; mi++) {
      const int rbase = m0 + wr * 64 + mi * 16 + kb * 4;
#pragma unroll
      for (int r = 0; r < 4; r++) {
        const float yv = fmaxf(acc[mi][nj][r], 0.f);
        ytmp[(size_t)(rbase + r) * 128 + c] = f2bf(yv);
        s += yv; s2 += yv * yv;
      }
    }
    s += __shfl_xor(s, 16);  s += __shfl_xor(s, 32);
    s2 += __shfl_xor(s2, 16); s2 += __shfl_xor(s2, 32);
    if (kb == 0) { redS[wr][c] = s; redS2[wr][c] = s2; }
  }
  __syncthreads();
  if (tid < 128) {
    partial[((size_t)blockIdx.y * 128 + tid) * 2]     = redS[0][tid] + redS[1][tid];
    partial[((size_t)blockIdx.y * 128 + tid) * 2 + 1] = redS2[0][tid] + redS2[1][tid];
  }
}

// ---------------- BN stats final reduce ----------------
__global__ __launch_bounds__(128) void k_bnstats2(const float* __restrict__ partial,
                                                  float* __restrict__ stats) {
  const int ch = threadIdx.x;
  float s = 0.f, s2 = 0.f;
  for (int i = 0; i < 512; i++) {
    s  += partial[(size_t)(i * 128 + ch) * 2];
    s2 += partial[(size_t)(i * 128 + ch) * 2 + 1];
  }
  const float mu = s * (1.f / 65536.f);
  const float var = s2 * (1.f / 65536.f) - mu * mu;
  stats[ch * 2] = mu;
  stats[ch * 2 + 1] = rsqrtf(var + 1e-5f);
}

// ---------------- BN apply + transpose to (B,E,H,W), coalesced writes -------
__global__ __launch_bounds__(256) void k_bnout(const short* __restrict__ y,
                                               const float* __restrict__ stats,
                                               const float* __restrict__ gamma,
                                               const float* __restrict__ beta,
                                               float* __restrict__ out) {
  const int bh = blockIdx.x;
  const int b = bh >> 7, h = bh & 127;
  const int w = threadIdx.x & 127, half = threadIdx.x >> 7;
  const short* yp = y + (size_t)(bh * 128 + w) * 128 + half * 64;
  float* op = out + ((size_t)(b * 128) << 14) + h * 128 + w;
#pragma unroll
  for (int e8 = 0; e8 < 8; e8++) {
    bf16x8 v = *(const bf16x8*)(yp + e8 * 8);
#pragma unroll
    for (int u = 0; u < 8; u++) {
      const int e = half * 64 + e8 * 8 + u;
      const float mu = stats[e * 2], rstd = stats[e * 2 + 1];
      op[(size_t)e << 14] = (bf2f(v[u]) - mu) * rstd * gamma[e] + beta[e];
    }
  }
}

// ---------------- launcher ----------------
extern "C" void kernel_launch(void* const* d_in, const int* in_sizes, int n_in,
                              void* d_out, int out_size, void* d_ws, size_t ws_size,
                              hipStream_t stream) {
  const float* x      = (const float*)d_in[0];
  const float* res    = (const float*)d_in[1];
  const float* wq_h   = (const float*)d_in[2];
  const float* wkv_h  = (const float*)d_in[3];
  const float* wo_h   = (const float*)d_in[4];
  const float* wob_h  = (const float*)d_in[5];
  const float* wq_w   = (const float*)d_in[6];
  const float* wkv_w  = (const float*)d_in[7];
  const float* wo_w   = (const float*)d_in[8];
  const float* wob_w  = (const float*)d_in[9];
  const float* conv_w = (const float*)d_in[10];
  const float* gamma  = (const float*)d_in[11];
  const float* beta   = (const float*)d_in[12];

  char* ws = (char*)d_ws;
  short* wqkvT[2] = {(short*)(ws + 0), (short*)(ws + 393216)};
  short* woT[2]   = {(short*)(ws + 786432), (short*)(ws + 917504)};
  short* convT    = (short*)(ws + 1048576);
  short* xu       = (short*)(ws + 1245184);
  short* ytmp     = (short*)(ws + 34799616);
  float* partial  = (float*)(ws + 51576832);
  float* stats    = (float*)(ws + 52101120);
  short* accb1    = (short*)(ws + 52102144);
  float* smg      = (float*)(ws + 85656576);
  short* accb0    = (short*)d_out;             // dir-0 axial output in d_out
  float* out      = (float*)d_out;

  if (ws_size < 87753728ull)
    fprintf(stderr, "kernel_launch: ws_size %zu too small\n", ws_size);

  // fused weight prep: starts 0,64,192,256,384,448,512; total 592 tiles
  WtAll P;
  P.src[0] = wq_h;  P.dst[0] = wqkvT[0];          P.K[0] = 256; P.N[0] = 256; P.tile0[0] = 0;
  P.src[1] = wkv_h; P.dst[1] = wqkvT[0] + 65536;  P.K[1] = 256; P.N[1] = 512; P.tile0[1] = 64;
  P.src[2] = wq_w;  P.dst[2] = wqkvT[1];          P.K[2] = 256; P.N[2] = 256; P.tile0[2] = 192;
  P.src[3] = wkv_w; P.dst[3] = wqkvT[1] + 65536;  P.K[3] = 256; P.N[3] = 512; P.tile0[3] = 256;
  P.src[4] = wo_h;  P.dst[4] = woT[0];            P.K[4] = 256; P.N[4] = 256; P.tile0[4] = 384;
  P.src[5] = wo_w;  P.dst[5] = woT[1];            P.K[5] = 256; P.N[5] = 256; P.tile0[5] = 448;
  P.src[6] = conv_w;P.dst[6] = convT;             P.K[6] = 640; P.N[6] = 128; P.tile0[6] = 512;
  k_wt_all<<<592, 256, 0, stream>>>(P);

  k_upsample<<<dim3(512, 4), 256, 0, stream>>>(x, xu);

  k_fused<<<dim3(512, 2), 1024, 0, stream>>>(xu, wqkvT[0], woT[0],
                                             wob_h, wob_w, accb0, accb1, smg);

  k_gemm_conv<<<dim3(1, 512), 256, 0, stream>>>(accb0, accb1, xu, res, convT,
                                                ytmp, partial);
  k_bnstats2<<<1, 128, 0, stream>>>(partial, stats);
  k_bnout<<<512, 256, 0, stream>>>(ytmp, stats, gamma, beta, out);
}

// Round 9
// 279.579 us; speedup vs baseline: 1.2768x; 1.1931x over previous
//
#include <hip/hip_runtime.h>
#include <hip/hip_bf16.h>
#include <cstdio>

// BlockAxialUp on MI355X, round 9: round-8 16-wave structure, spills fixed.
//  - __launch_bounds__(1024, 4): VGPR cap 128 (round 8 defaulted to 64 -> 400MB
//    scratch traffic, the whole regression)
//  - production split into Q+K pass and V pass (peak live regs ~90 < 128)
//  - ytmp back to f32 (absmax margin)
//
// ws layout (bytes):
//   0         wqkvT_h bf16 [768][256] (q 0:256, k 256:512, v 512:768)
//   393216    wqkvT_w
//   786432    woT_h  bf16 [256][256]
//   917504    woT_w
//   1048576   convT  bf16 [128][640]
//   1245184   xu     bf16 [65536][256]
//   34799616  ytmp   f32  [65536][128]
//   68354048  partial f32 [512][128][2]
//   68878336  stats  f32  [128][2]
//   68879360  accb1  bf16 [65536][256]
//   102433792 sm     f32  [1024 blocks][512]   (softmax (m,l) exchange)
//   -> end 104530944
// accb0 (dir-0) lives in d_out; final f32 output overwrites it.

typedef short bf16x8 __attribute__((ext_vector_type(8)));
typedef short bf16x4 __attribute__((ext_vector_type(4)));
typedef float f32x4 __attribute__((ext_vector_type(4)));

#define MFMA16(a, b, c) __builtin_amdgcn_mfma_f32_16x16x32_bf16((a), (b), (c), 0, 0, 0)

__device__ __forceinline__ short f2bf(float v) {
  __hip_bfloat16 h = __float2bfloat16(v);
  union { __hip_bfloat16 h; short s; } u; u.h = h; return u.s;
}
__device__ __forceinline__ float bf2f(short s) {
  return __uint_as_float(((unsigned int)(unsigned short)s) << 16);
}
// XOR swizzle, granule = 8 shorts (16 B); flips col bits 3-5 only.
__device__ __forceinline__ int swz(int row, int col) {
  return col ^ ((row & 7) << 3);
}

// ---------------- fused weight prep: dst[n][k] = bf16(src[k][n]) ------------
struct WtAll {
  const float* src[7];
  short* dst[7];
  int K[7], N[7], tile0[7];
};

__global__ __launch_bounds__(256) void k_wt_all(WtAll P) {
  const int bid = blockIdx.x;
  int i = 0;
#pragma unroll
  for (int j = 1; j < 7; j++) if (bid >= P.tile0[j]) i = j;
  const float* src = P.src[i];
  short* dst = P.dst[i];
  const int K = P.K[i], N = P.N[i];
  const int local = bid - P.tile0[i];
  const int ktiles = K >> 5;
  const int nt = local / ktiles, kt = local - nt * ktiles;
  const int k0 = kt * 32, n0 = nt * 32;
  __shared__ float tile[32][33];
  const int tx = threadIdx.x & 31, ty = threadIdx.x >> 5;
#pragma unroll
  for (int r = 0; r < 4; r++)
    tile[ty + r * 8][tx] = src[(size_t)(k0 + ty + r * 8) * N + n0 + tx];
  __syncthreads();
#pragma unroll
  for (int r = 0; r < 4; r++)
    dst[(size_t)(n0 + ty + r * 8) * K + k0 + tx] = f2bf(tile[tx][ty + r * 8]);
}

// ---------------- upsample 2x bilinear align_corners --------------------
__global__ __launch_bounds__(256) void k_upsample(const float* __restrict__ x,
                                                  short* __restrict__ xu) {
  __shared__ float ldsV[64][65];
  const int bh = blockIdx.x, z = blockIdx.y;
  const int b = bh >> 7, h = bh & 127;
  const float chf = h * (63.0f / 127.0f);
  int i0 = (int)chf; if (i0 > 62) i0 = 62;
  const float wh = chf - (float)i0;
  const int t = threadIdx.x;
  const int cbase = z * 64;
  const float* xb = x + ((size_t)(b * 256 + cbase) * 64 + i0) * 64;
#pragma unroll
  for (int p = 0; p < 16; p++) {
    const int li = p * 256 + t;
    const int c = li >> 6, w = li & 63;
    const float* px = xb + (size_t)c * 4096 + w;
    const float v0 = px[0], v1 = px[64];
    ldsV[c][w] = v0 * (1.f - wh) + v1 * wh;
  }
  __syncthreads();
  const int cg = t & 7, wi = t >> 3;
  short* xout = xu + (size_t)(bh * 128) * 256 + cbase + cg * 8;
#pragma unroll
  for (int p = 0; p < 4; p++) {
    const int w = p * 32 + wi;
    const float cwf = w * (63.0f / 127.0f);
    int j0 = (int)cwf; if (j0 > 62) j0 = 62;
    const float ww = cwf - (float)j0;
    bf16x8 o;
#pragma unroll
    for (int u = 0; u < 8; u++) {
      const float v0 = ldsV[cg * 8 + u][j0], v1 = ldsV[cg * 8 + u][j0 + 1];
      o[u] = f2bf(v0 * (1.f - ww) + v1 * ww);
    }
    *(bf16x8*)(xout + (size_t)w * 256) = o;
  }
}

// ---------------- fused QKV + attention + proj --------------------------
// grid (512, 2): blockIdx.x = sequence, blockIdx.y = dir.
// 1024 thr = 16 waves: grp = wid>>3 (token/key/chan half), sw = wid&7.
// LDS: Xs 64K + Qb(P) 32K + Kb(O) 32K + Vtb 32K = 160 KB -> 1 blk/CU, 4 w/SIMD.
__global__ __launch_bounds__(1024, 4) void k_fused(const short* __restrict__ xu,
                                                   const short* __restrict__ wqkvT0,
                                                   const short* __restrict__ woT0,
                                                   const float* __restrict__ wob0,
                                                   const float* __restrict__ wob1,
                                                   short* __restrict__ accb0,
                                                   short* __restrict__ accb1,
                                                   float* __restrict__ smg) {
  __shared__ __align__(16) short Xs[128][256];
  __shared__ __align__(16) short Qb[128][128];   // Q, then P
  __shared__ __align__(16) short Kb[128][128];   // K, then O
  __shared__ __align__(16) short Vtb[128][128];  // V^T

  const int dir = blockIdx.y;
  const short* wqkvT = wqkvT0 + (size_t)dir * 196608;
  const short* woT   = woT0 + (size_t)dir * 65536;
  const float* wob   = dir ? wob1 : wob0;
  short* accb        = dir ? accb1 : accb0;
  float* sm = smg + (size_t)(blockIdx.y * 512 + blockIdx.x) * 512;  // [2][128][2] f32

  const int s = blockIdx.x;
  const int b = s >> 7, pos = s & 127;
  const int tok0 = b * 16384 + (dir ? pos * 128 : pos);
  const int tstep = dir ? 1 : 128;
  const int tid = threadIdx.x;
  const int lane = tid & 63, wid = tid >> 6;
  const int lr = lane & 15, kb = lane >> 4;
  const int grp = wid >> 3, sw = wid & 7;
  const int ct = sw * 16;                     // chan tile (prod) / token tile (attn)
  const float scale = 0.08838834764831845f;  // 128^-0.5

  // ---- stage Xs: 32 lanes cover one 512 B token row ----
#pragma unroll
  for (int p = 0; p < 4; p++) {
    const int u = p * 1024 + tid;
    const int row = u >> 5, ck = (u & 31) * 8;
    bf16x8 v = *(const bf16x8*)(xu + (size_t)(tok0 + row * tstep) * 256 + ck);
    *(bf16x8*)&Xs[row][swz(row, ck)] = v;
  }

  f32x4 accp[8];
#pragma unroll
  for (int i = 0; i < 8; i++) accp[i] = (f32x4){0.f, 0.f, 0.f, 0.f};

  for (int h = 0; h < 2; h++) {
    __syncthreads();  // A: Xs staged (h=0) / prev head's proj reads of Kb done

    // ---- production pass 1: Q,K for chans ct..ct+15, tokens grp*64..+63 ----
    {
      const short* wqb = wqkvT + (size_t)(h * 128 + ct + lr) * 256 + kb * 8;
      const short* wkb = wqkvT + (size_t)(256 + h * 128 + ct + lr) * 256 + kb * 8;
      f32x4 dq[4], dk[4];
#pragma unroll
      for (int i = 0; i < 4; i++) {
        dq[i] = (f32x4){0.f, 0.f, 0.f, 0.f};
        dk[i] = (f32x4){0.f, 0.f, 0.f, 0.f};
      }
#pragma unroll
      for (int ks = 0; ks < 8; ks++) {
        bf16x8 fq = *(const bf16x8*)(wqb + ks * 32);
        bf16x8 fk = *(const bf16x8*)(wkb + ks * 32);
#pragma unroll
        for (int i = 0; i < 4; i++) {
          const int xrow = (grp * 4 + i) * 16 + lr;
          bf16x8 xf = *(const bf16x8*)&Xs[xrow][swz(xrow, kb * 8 + ks * 32)];
          dq[i] = MFMA16(fq, xf, dq[i]);   // D[chan][token]
          dk[i] = MFMA16(fk, xf, dk[i]);   // D[chan][token]
        }
      }
#pragma unroll
      for (int i = 0; i < 4; i++) {
        const int nt = grp * 4 + i;
        const int trow = nt * 16 + lr, cc = ct + kb * 4;
        bf16x4 pq = {f2bf(dq[i][0]), f2bf(dq[i][1]), f2bf(dq[i][2]), f2bf(dq[i][3])};
        bf16x4 pk = {f2bf(dk[i][0]), f2bf(dk[i][1]), f2bf(dk[i][2]), f2bf(dk[i][3])};
        *(bf16x4*)&Qb[trow][swz(trow, cc)] = pq;
        *(bf16x4*)&Kb[trow][swz(trow, cc)] = pk;
      }
    }
    // ---- production pass 2: V^T (swapped operands -> D[token][chan]) ----
    {
      const short* wvb = wqkvT + (size_t)(512 + h * 128 + ct + lr) * 256 + kb * 8;
      f32x4 dv[4];
#pragma unroll
      for (int i = 0; i < 4; i++) dv[i] = (f32x4){0.f, 0.f, 0.f, 0.f};
#pragma unroll
      for (int ks = 0; ks < 8; ks++) {
        bf16x8 fv = *(const bf16x8*)(wvb + ks * 32);
#pragma unroll
        for (int i = 0; i < 4; i++) {
          const int xrow = (grp * 4 + i) * 16 + lr;
          bf16x8 xf = *(const bf16x8*)&Xs[xrow][swz(xrow, kb * 8 + ks * 32)];
          dv[i] = MFMA16(xf, fv, dv[i]);   // D[token][chan]
        }
      }
#pragma unroll
      for (int i = 0; i < 4; i++) {
        const int nt = grp * 4 + i;
        const int vrow = ct + lr;
        bf16x4 pv = {f2bf(dv[i][0]), f2bf(dv[i][1]), f2bf(dv[i][2]), f2bf(dv[i][3])};
        *(bf16x4*)&Vtb[vrow][swz(vrow, nt * 16 + kb * 4)] = pv;
      }
    }

    __syncthreads();  // B: Q/K/Vt visible to all waves

    // ---- S^T = K Q^T : q-tokens ct+lr, keys grp*64..+63 (split) ----
    f32x4 s8[4];
#pragma unroll
    for (int i = 0; i < 4; i++) s8[i] = (f32x4){0.f, 0.f, 0.f, 0.f};
    const int qrow = ct + lr;
#pragma unroll
    for (int ks = 0; ks < 4; ks++) {
      bf16x8 aq = *(const bf16x8*)&Qb[qrow][swz(qrow, kb * 8 + ks * 32)];
#pragma unroll
      for (int j = 0; j < 4; j++) {
        const int krow = (grp * 4 + j) * 16 + lr;
        bf16x8 bk = *(const bf16x8*)&Kb[krow][swz(krow, kb * 8 + ks * 32)];
        s8[j] = MFMA16(bk, aq, s8[j]);   // D[k-token][q-token]
      }
    }
    // partial softmax over own 64 keys (in-lane 16 + xor 16,32 over kb)
    float m = s8[0][0];
#pragma unroll
    for (int j = 0; j < 4; j++)
#pragma unroll
      for (int r = 0; r < 4; r++) m = fmaxf(m, s8[j][r]);
    m = fmaxf(m, __shfl_xor(m, 16));
    m = fmaxf(m, __shfl_xor(m, 32));
    float l = 0.f;
#pragma unroll
    for (int j = 0; j < 4; j++)
#pragma unroll
      for (int r = 0; r < 4; r++) l += __expf((s8[j][r] - m) * scale);
    l += __shfl_xor(l, 16);
    l += __shfl_xor(l, 32);
    if (kb == 0) {
      sm[grp * 256 + (ct + lr) * 2]     = m;
      sm[grp * 256 + (ct + lr) * 2 + 1] = l;
    }

    __syncthreads();  // C: SM written; all S reads of Qb/Kb done

    // merge (m,l) with other grp; compute P for own keys; write into Qb
    {
      const int og = 1 - grp;
      const float mo = sm[og * 256 + (ct + lr) * 2];
      const float lo = sm[og * 256 + (ct + lr) * 2 + 1];
      const float M = fmaxf(m, mo);
      const float L = l * __expf((m - M) * scale) + lo * __expf((mo - M) * scale);
      const float inv = 1.f / L;
#pragma unroll
      for (int j = 0; j < 4; j++) {
        bf16x4 pp = {f2bf(__expf((s8[j][0] - M) * scale) * inv),
                     f2bf(__expf((s8[j][1] - M) * scale) * inv),
                     f2bf(__expf((s8[j][2] - M) * scale) * inv),
                     f2bf(__expf((s8[j][3] - M) * scale) * inv)};
        *(bf16x4*)&Qb[qrow][swz(qrow, (grp * 4 + j) * 16 + kb * 4)] = pp;
      }
    }

    __syncthreads();  // D: full P visible

    // ---- O = P V : own q-tokens, chans grp*64..+63 (split) ----
    f32x4 o8[4];
#pragma unroll
    for (int i = 0; i < 4; i++) o8[i] = (f32x4){0.f, 0.f, 0.f, 0.f};
#pragma unroll
    for (int ks = 0; ks < 4; ks++) {
      bf16x8 bp = *(const bf16x8*)&Qb[qrow][swz(qrow, kb * 8 + ks * 32)];
#pragma unroll
      for (int mi = 0; mi < 4; mi++) {
        const int vrow = (grp * 4 + mi) * 16 + lr;
        bf16x8 av = *(const bf16x8*)&Vtb[vrow][swz(vrow, kb * 8 + ks * 32)];
        o8[mi] = MFMA16(av, bp, o8[mi]);   // D[chan][q-token]
      }
    }
#pragma unroll
    for (int mi = 0; mi < 4; mi++) {
      const int cc = (grp * 4 + mi) * 16 + kb * 4;
      bf16x4 po = {f2bf(o8[mi][0]), f2bf(o8[mi][1]), f2bf(o8[mi][2]), f2bf(o8[mi][3])};
      *(bf16x4*)&Kb[qrow][swz(qrow, cc)] = po;
    }

    __syncthreads();  // E: O complete

    // ---- proj: own 16 out-chans (wid*16..+15), all tokens ----
    {
      const short* wp = woT + (size_t)(wid * 16 + lr) * 256 + h * 128 + kb * 8;
      bf16x8 w4[4];
#pragma unroll
      for (int ks = 0; ks < 4; ks++) w4[ks] = *(const bf16x8*)(wp + ks * 32);
#pragma unroll
      for (int nt = 0; nt < 8; nt++) {
        const int trow = nt * 16 + lr;
#pragma unroll
        for (int ks = 0; ks < 4; ks++) {
          bf16x8 bo = *(const bf16x8*)&Kb[trow][swz(trow, kb * 8 + ks * 32)];
          accp[nt] = MFMA16(w4[ks], bo, accp[nt]);   // D[outc][token]
        }
      }
    }
  }

  // ---- accb write: token = nt*16+lr, outc = wid*16 + kb*4 + r ----
  const int outc = wid * 16 + kb * 4;
  const float b0 = wob[outc], b1 = wob[outc + 1];
  const float b2 = wob[outc + 2], b3 = wob[outc + 3];
#pragma unroll
  for (int nt = 0; nt < 8; nt++) {
    const int token = tok0 + (nt * 16 + lr) * tstep;
    bf16x4 pv = {f2bf(accp[nt][0] + b0), f2bf(accp[nt][1] + b1),
                 f2bf(accp[nt][2] + b2), f2bf(accp[nt][3] + b3)};
    *(bf16x4*)(accb + (size_t)token * 256 + outc) = pv;
  }
}

// ---- conv1x1: [relu(a0+a1)|xu|res] @ convT^T -> relu -> ytmp(f32) + BN partials
__global__ __launch_bounds__(256) void k_gemm_conv(const short* __restrict__ accb0,
                                                   const short* __restrict__ accb1,
                                                   const short* __restrict__ xu,
                                                   const float* __restrict__ res,
                                                   const short* __restrict__ Bt,
                                                   float* __restrict__ ytmp,
                                                   float* __restrict__ partial) {
  __shared__ float redS[2][128], redS2[2][128];
  const int tid = threadIdx.x;
  const int lane = tid & 63, wid = tid >> 6;
  const int lr = lane & 15, kb = lane >> 4;
  const int wr = wid >> 1, wc = wid & 1;
  const int m0 = blockIdx.y * 128;
  f32x4 acc[4][4];
#pragma unroll
  for (int i = 0; i < 4; i++)
#pragma unroll
    for (int j = 0; j < 4; j++) acc[i][j] = (f32x4){0.f, 0.f, 0.f, 0.f};
  const short* arow0 = accb0 + (size_t)(m0 + wr * 64 + lr) * 256 + kb * 8;
  const short* arow1 = accb1 + (size_t)(m0 + wr * 64 + lr) * 256 + kb * 8;
  const short* arow2 = xu + (size_t)(m0 + wr * 64 + lr) * 256 + kb * 8;
  const short* brow = Bt + (size_t)(wc * 64 + lr) * 640 + kb * 8;
#pragma unroll
  for (int ks = 0; ks < 8; ks++) {
    bf16x8 a[4], b[4];
#pragma unroll
    for (int mi = 0; mi < 4; mi++) {
      bf16x8 t0 = *(const bf16x8*)(arow0 + (size_t)mi * 16 * 256 + ks * 32);
      bf16x8 t1 = *(const bf16x8*)(arow1 + (size_t)mi * 16 * 256 + ks * 32);
      bf16x8 tv;
#pragma unroll
      for (int u = 0; u < 8; u++) {
        float sv = bf2f(t0[u]) + bf2f(t1[u]);
        tv[u] = f2bf(fmaxf(sv, 0.f));
      }
      a[mi] = tv;
    }
#pragma unroll
    for (int nj = 0; nj < 4; nj++)
      b[nj] = *(const bf16x8*)(brow + (size_t)nj * 16 * 640 + ks * 32);
#pragma unroll
    for (int mi = 0; mi < 4; mi++)
#pragma unroll
      for (int nj = 0; nj < 4; nj++)
        acc[mi][nj] = MFMA16(a[mi], b[nj], acc[mi][nj]);
  }
#pragma unroll
  for (int ks = 8; ks < 16; ks++) {
    bf16x8 a[4], b[4];
#pragma unroll
    for (int mi = 0; mi < 4; mi++)
      a[mi] = *(const bf16x8*)(arow2 + (size_t)mi * 16 * 256 + (ks - 8) * 32);
#pragma unroll
    for (int nj = 0; nj < 4; nj++)
      b[nj] = *(const bf16x8*)(brow + (size_t)nj * 16 * 640 + ks * 32);
#pragma unroll
    for (int mi = 0; mi < 4; mi++)
#pragma unroll
      for (int nj = 0; nj < 4; nj++)
        acc[mi][nj] = MFMA16(a[mi], b[nj], acc[mi][nj]);
  }
  const int bC = (m0 >> 14) * 128;
  const int hh = (m0 >> 7) & 127;
#pragma unroll
  for (int ks = 16; ks < 20; ks++) {
    const int e0 = (ks - 16) * 32 + kb * 8;
    bf16x8 a[4], b[4];
#pragma unroll
    for (int mi = 0; mi < 4; mi++) {
      const int wl = wr * 64 + mi * 16 + lr;
      const float* rp = res + ((size_t)(bC + e0) * 128 + hh) * 128 + wl;
      bf16x8 tv;
#pragma unroll
      for (int u = 0; u < 8; u++) tv[u] = f2bf(rp[(size_t)u * 16384]);
      a[mi] = tv;
    }
#pragma unroll
    for (int nj = 0; nj < 4; nj++)
      b[nj] = *(const bf16x8*)(brow + (size_t)nj * 16 * 640 + ks * 32);
#pragma unroll
    for (int mi = 0; mi < 4; mi++)
#pragma unroll
      for (int nj = 0; nj < 4; nj++)
        acc[mi][nj] = MFMA16(a[mi], b[nj], acc[mi][nj]);
  }
  // epilogue: relu -> f32 ytmp + per-channel partial sums (exact f32)
#pragma unroll
  for (int nj = 0; nj < 4; nj++) {
    float s = 0.f, s2 = 0.f;
    const int c = wc * 64 + nj * 16 + lr;
#pragma unroll
    for (int mi = 0; mi < 4; mi++) {
      const int rbase = m0 + wr * 64 + mi * 16 + kb * 4;
#pragma unroll
      for (int r = 0; r < 4; r++) {
        const float yv = fmaxf(acc[mi][nj][r], 0.f);
        ytmp[(size_t)(rbase + r) * 128 + c] = yv;
        s += yv; s2 += yv * yv;
      }
    }
    s += __shfl_xor(s, 16);  s += __shfl_xor(s, 32);
    s2 += __shfl_xor(s2, 16); s2 += __shfl_xor(s2, 32);
    if (kb == 0) { redS[wr][c] = s; redS2[wr][c] = s2; }
  }
  __syncthreads();
  if (tid < 128) {
    partial[((size_t)blockIdx.y * 128 + tid) * 2]     = redS[0][tid] + redS[1][tid];
    partial[((size_t)blockIdx.y * 128 + tid) * 2 + 1] = redS2[0][tid] + redS2[1][tid];
  }
}

// ---------------- BN stats final reduce ----------------
__global__ __launch_bounds__(128) void k_bnstats2(const float* __restrict__ partial,
                                                  float* __restrict__ stats) {
  const int ch = threadIdx.x;
  float s = 0.f, s2 = 0.f;
  for (int i = 0; i < 512; i++) {
    s  += partial[(size_t)(i * 128 + ch) * 2];
    s2 += partial[(size_t)(i * 128 + ch) * 2 + 1];
  }
  const float mu = s * (1.f / 65536.f);
  const float var = s2 * (1.f / 65536.f) - mu * mu;
  stats[ch * 2] = mu;
  stats[ch * 2 + 1] = rsqrtf(var + 1e-5f);
}

// ---------------- BN apply + transpose to (B,E,H,W), coalesced writes -------
__global__ __launch_bounds__(256) void k_bnout(const float* __restrict__ y,
                                               const float* __restrict__ stats,
                                               const float* __restrict__ gamma,
                                               const float* __restrict__ beta,
                                               float* __restrict__ out) {
  const int bh = blockIdx.x;
  const int b = bh >> 7, h = bh & 127;
  const int w = threadIdx.x & 127, half = threadIdx.x >> 7;
  const float* yp = y + (size_t)(bh * 128 + w) * 128 + half * 64;
  float* op = out + ((size_t)(b * 128) << 14) + h * 128 + w;
#pragma unroll
  for (int e4 = 0; e4 < 16; e4++) {
    f32x4 v = *(const f32x4*)(yp + e4 * 4);
#pragma unroll
    for (int u = 0; u < 4; u++) {
      const int e = half * 64 + e4 * 4 + u;
      const float mu = stats[e * 2], rstd = stats[e * 2 + 1];
      op[(size_t)e << 14] = (v[u] - mu) * rstd * gamma[e] + beta[e];
    }
  }
}

// ---------------- launcher ----------------
extern "C" void kernel_launch(void* const* d_in, const int* in_sizes, int n_in,
                              void* d_out, int out_size, void* d_ws, size_t ws_size,
                              hipStream_t stream) {
  const float* x      = (const float*)d_in[0];
  const float* res    = (const float*)d_in[1];
  const float* wq_h   = (const float*)d_in[2];
  const float* wkv_h  = (const float*)d_in[3];
  const float* wo_h   = (const float*)d_in[4];
  const float* wob_h  = (const float*)d_in[5];
  const float* wq_w   = (const float*)d_in[6];
  const float* wkv_w  = (const float*)d_in[7];
  const float* wo_w   = (const float*)d_in[8];
  const float* wob_w  = (const float*)d_in[9];
  const float* conv_w = (const float*)d_in[10];
  const float* gamma  = (const float*)d_in[11];
  const float* beta   = (const float*)d_in[12];

  char* ws = (char*)d_ws;
  short* wqkvT[2] = {(short*)(ws + 0), (short*)(ws + 393216)};
  short* woT[2]   = {(short*)(ws + 786432), (short*)(ws + 917504)};
  short* convT    = (short*)(ws + 1048576);
  short* xu       = (short*)(ws + 1245184);
  float* ytmp     = (float*)(ws + 34799616);
  float* partial  = (float*)(ws + 68354048);
  float* stats    = (float*)(ws + 68878336);
  short* accb1    = (short*)(ws + 68879360);
  float* smg      = (float*)(ws + 102433792);
  short* accb0    = (short*)d_out;             // dir-0 axial output in d_out
  float* out      = (float*)d_out;

  if (ws_size < 104530944ull)
    fprintf(stderr, "kernel_launch: ws_size %zu too small\n", ws_size);

  // fused weight prep: starts 0,64,192,256,384,448,512; total 592 tiles
  WtAll P;
  P.src[0] = wq_h;  P.dst[0] = wqkvT[0];          P.K[0] = 256; P.N[0] = 256; P.tile0[0] = 0;
  P.src[1] = wkv_h; P.dst[1] = wqkvT[0] + 65536;  P.K[1] = 256; P.N[1] = 512; P.tile0[1] = 64;
  P.src[2] = wq_w;  P.dst[2] = wqkvT[1];          P.K[2] = 256; P.N[2] = 256; P.tile0[2] = 192;
  P.src[3] = wkv_w; P.dst[3] = wqkvT[1] + 65536;  P.K[3] = 256; P.N[3] = 512; P.tile0[3] = 256;
  P.src[4] = wo_h;  P.dst[4] = woT[0];            P.K[4] = 256; P.N[4] = 256; P.tile0[4] = 384;
  P.src[5] = wo_w;  P.dst[5] = woT[1];            P.K[5] = 256; P.N[5] = 256; P.tile0[5] = 448;
  P.src[6] = conv_w;P.dst[6] = convT;             P.K[6] = 640; P.N[6] = 128; P.tile0[6] = 512;
  k_wt_all<<<592, 256, 0, stream>>>(P);

  k_upsample<<<dim3(512, 4), 256, 0, stream>>>(x, xu);

  k_fused<<<dim3(512, 2), 1024, 0, stream>>>(xu, wqkvT[0], woT[0],
                                             wob_h, wob_w, accb0, accb1, smg);

  k_gemm_conv<<<dim3(1, 512), 256, 0, stream>>>(accb0, accb1, xu, res, convT,
                                                ytmp, partial);
  k_bnstats2<<<1, 128, 0, stream>>>(partial, stats);
  k_bnout<<<512, 256, 0, stream>>>(ytmp, stats, gamma, beta, out);
}

// Round 10
// 248.002 us; speedup vs baseline: 1.4394x; 1.1273x over previous
//
#include <hip/hip_runtime.h>
#include <hip/hip_bf16.h>
#include <cstdio>

// BlockAxialUp on MI355X, round 10: consolidation of proven-best pieces.
//  - fused kernel: round-6 8-wave body (best measured: 42.8us/block, VGPR 124,
//    no spills) - r7 shfl-repack and r8/r9 16-wave experiments reverted.
//  - merged direction dispatch grid(512,2), separate accumulators (r7-proven),
//    conv sums relu(a0+a1).
//  - r9 tail: BN partials fused into conv epilogue, f32 ytmp, coalesced bnout.
//
// ws layout (bytes):
//   0         wqkvT_h bf16 [768][256] (q 0:256, k 256:512, v 512:768)
//   393216    wqkvT_w
//   786432    woT_h  bf16 [256][256]
//   917504    woT_w
//   1048576   convT  bf16 [128][640]
//   1245184   xu     bf16 [65536][256]
//   34799616  ytmp   f32  [65536][128]
//   68354048  partial f32 [512][128][2]
//   68878336  stats  f32  [128][2]
//   68879360  accb1  bf16 [65536][256]  -> end 102433792
// accb0 (dir-0) lives in d_out; final f32 output overwrites it.

typedef short bf16x8 __attribute__((ext_vector_type(8)));
typedef short bf16x4 __attribute__((ext_vector_type(4)));
typedef float f32x4 __attribute__((ext_vector_type(4)));

#define MFMA16(a, b, c) __builtin_amdgcn_mfma_f32_16x16x32_bf16((a), (b), (c), 0, 0, 0)

__device__ __forceinline__ short f2bf(float v) {
  __hip_bfloat16 h = __float2bfloat16(v);
  union { __hip_bfloat16 h; short s; } u; u.h = h; return u.s;
}
__device__ __forceinline__ float bf2f(short s) {
  return __uint_as_float(((unsigned int)(unsigned short)s) << 16);
}
// XOR swizzle, granule = 8 shorts (16 B); flips col bits 3-5 only.
__device__ __forceinline__ int swz(int row, int col) {
  return col ^ ((row & 7) << 3);
}

// ---------------- fused weight prep: dst[n][k] = bf16(src[k][n]) ------------
struct WtAll {
  const float* src[7];
  short* dst[7];
  int K[7], N[7], tile0[7];
};

__global__ __launch_bounds__(256) void k_wt_all(WtAll P) {
  const int bid = blockIdx.x;
  int i = 0;
#pragma unroll
  for (int j = 1; j < 7; j++) if (bid >= P.tile0[j]) i = j;
  const float* src = P.src[i];
  short* dst = P.dst[i];
  const int K = P.K[i], N = P.N[i];
  const int local = bid - P.tile0[i];
  const int ktiles = K >> 5;
  const int nt = local / ktiles, kt = local - nt * ktiles;
  const int k0 = kt * 32, n0 = nt * 32;
  __shared__ float tile[32][33];
  const int tx = threadIdx.x & 31, ty = threadIdx.x >> 5;
#pragma unroll
  for (int r = 0; r < 4; r++)
    tile[ty + r * 8][tx] = src[(size_t)(k0 + ty + r * 8) * N + n0 + tx];
  __syncthreads();
#pragma unroll
  for (int r = 0; r < 4; r++)
    dst[(size_t)(n0 + ty + r * 8) * K + k0 + tx] = f2bf(tile[tx][ty + r * 8]);
}

// ---------------- upsample 2x bilinear align_corners --------------------
__global__ __launch_bounds__(256) void k_upsample(const float* __restrict__ x,
                                                  short* __restrict__ xu) {
  __shared__ float ldsV[64][65];
  const int bh = blockIdx.x, z = blockIdx.y;
  const int b = bh >> 7, h = bh & 127;
  const float chf = h * (63.0f / 127.0f);
  int i0 = (int)chf; if (i0 > 62) i0 = 62;
  const float wh = chf - (float)i0;
  const int t = threadIdx.x;
  const int cbase = z * 64;
  const float* xb = x + ((size_t)(b * 256 + cbase) * 64 + i0) * 64;
#pragma unroll
  for (int p = 0; p < 16; p++) {
    const int li = p * 256 + t;
    const int c = li >> 6, w = li & 63;
    const float* px = xb + (size_t)c * 4096 + w;
    const float v0 = px[0], v1 = px[64];
    ldsV[c][w] = v0 * (1.f - wh) + v1 * wh;
  }
  __syncthreads();
  const int cg = t & 7, wi = t >> 3;
  short* xout = xu + (size_t)(bh * 128) * 256 + cbase + cg * 8;
#pragma unroll
  for (int p = 0; p < 4; p++) {
    const int w = p * 32 + wi;
    const float cwf = w * (63.0f / 127.0f);
    int j0 = (int)cwf; if (j0 > 62) j0 = 62;
    const float ww = cwf - (float)j0;
    bf16x8 o;
#pragma unroll
    for (int u = 0; u < 8; u++) {
      const float v0 = ldsV[cg * 8 + u][j0], v1 = ldsV[cg * 8 + u][j0 + 1];
      o[u] = f2bf(v0 * (1.f - ww) + v1 * ww);
    }
    *(bf16x8*)(xout + (size_t)w * 256) = o;
  }
}

// ---------------- fused QKV + attention + proj (round-6 body) ---------------
// grid (512, 2): blockIdx.x = sequence, blockIdx.y = dir. 512 thr = 8 waves.
// LDS: Xs 64K + Qb(P) 32K + Kb(O) 32K + Vtb 32K = 160 KB.
__global__ __launch_bounds__(512, 2) void k_fused(const short* __restrict__ xu,
                                                  const short* __restrict__ wqkvT0,
                                                  const short* __restrict__ woT0,
                                                  const float* __restrict__ wob0,
                                                  const float* __restrict__ wob1,
                                                  short* __restrict__ accb0,
                                                  short* __restrict__ accb1) {
  __shared__ __align__(16) short Xs[128][256];
  __shared__ __align__(16) short Qb[128][128];   // Q, then P
  __shared__ __align__(16) short Kb[128][128];   // K, then O
  __shared__ __align__(16) short Vtb[128][128];  // V^T

  const int dir = blockIdx.y;
  const short* wqkvT = wqkvT0 + (size_t)dir * 196608;
  const short* woT   = woT0 + (size_t)dir * 65536;
  const float* wob   = dir ? wob1 : wob0;
  short* accb        = dir ? accb1 : accb0;

  const int s = blockIdx.x;
  const int b = s >> 7, pos = s & 127;
  const int tok0 = b * 16384 + (dir ? pos * 128 : pos);
  const int tstep = dir ? 1 : 128;
  const int tid = threadIdx.x;
  const int lane = tid & 63, wid = tid >> 6;
  const int lr = lane & 15, kb = lane >> 4;
  const int ct = wid * 16;                    // wave's chan/token tile base
  const float scale = 0.08838834764831845f;  // 128^-0.5

  // ---- stage Xs: 32 lanes cover one 512 B token row ----
#pragma unroll
  for (int p = 0; p < 8; p++) {
    const int u = p * 512 + tid;
    const int row = u >> 5, ck = (u & 31) * 8;
    bf16x8 v = *(const bf16x8*)(xu + (size_t)(tok0 + row * tstep) * 256 + ck);
    *(bf16x8*)&Xs[row][swz(row, ck)] = v;
  }

  f32x4 accp[2][8];
#pragma unroll
  for (int i = 0; i < 2; i++)
#pragma unroll
    for (int j = 0; j < 8; j++) accp[i][j] = (f32x4){0.f, 0.f, 0.f, 0.f};

  for (int h = 0; h < 2; h++) {
    // weight fragments for this head (L1/L2-hot, identical across blocks)
    const short* wqb = wqkvT + (size_t)(h * 128 + ct + lr) * 256 + kb * 8;
    const short* wkb = wqkvT + (size_t)(256 + h * 128 + ct + lr) * 256 + kb * 8;
    const short* wvb = wqkvT + (size_t)(512 + h * 128 + ct + lr) * 256 + kb * 8;
    bf16x8 wq[8], wk[8], wv[8];
#pragma unroll
    for (int ks = 0; ks < 8; ks++) {
      wq[ks] = *(const bf16x8*)(wqb + ks * 32);
      wk[ks] = *(const bf16x8*)(wkb + ks * 32);
      wv[ks] = *(const bf16x8*)(wvb + ks * 32);
    }

    __syncthreads();  // A: Xs staged (h=0) / prev head's proj reads done

    // ---- merged Q/K/V production: one pass over Xs ----
#pragma unroll
    for (int nt = 0; nt < 8; nt++) {
      const int xrow = nt * 16 + lr;
      f32x4 dq = (f32x4){0.f, 0.f, 0.f, 0.f};
      f32x4 dk = (f32x4){0.f, 0.f, 0.f, 0.f};
      f32x4 dv = (f32x4){0.f, 0.f, 0.f, 0.f};
#pragma unroll
      for (int ks = 0; ks < 8; ks++) {
        bf16x8 xf = *(const bf16x8*)&Xs[xrow][swz(xrow, kb * 8 + ks * 32)];
        dq = MFMA16(wq[ks], xf, dq);   // D[chan][token]
        dk = MFMA16(wk[ks], xf, dk);   // D[chan][token]
        dv = MFMA16(xf, wv[ks], dv);   // swapped: D[token][chan]
      }
      const int trow = nt * 16 + lr, cc = ct + kb * 4;
      bf16x4 pq = {f2bf(dq[0]), f2bf(dq[1]), f2bf(dq[2]), f2bf(dq[3])};
      bf16x4 pk = {f2bf(dk[0]), f2bf(dk[1]), f2bf(dk[2]), f2bf(dk[3])};
      *(bf16x4*)&Qb[trow][swz(trow, cc)] = pq;
      *(bf16x4*)&Kb[trow][swz(trow, cc)] = pk;
      const int vrow = ct + lr;
      bf16x4 pv = {f2bf(dv[0]), f2bf(dv[1]), f2bf(dv[2]), f2bf(dv[3])};
      *(bf16x4*)&Vtb[vrow][swz(vrow, nt * 16 + kb * 4)] = pv;
    }

    __syncthreads();  // B: Q/K/Vt visible to all waves

    // ---- S^T = K Q^T : lane owns q-token ct+lr ----
    f32x4 s8[8];
#pragma unroll
    for (int i = 0; i < 8; i++) s8[i] = (f32x4){0.f, 0.f, 0.f, 0.f};
    const int qrow = ct + lr;
#pragma unroll
    for (int ks = 0; ks < 4; ks++) {
      bf16x8 aq = *(const bf16x8*)&Qb[qrow][swz(qrow, kb * 8 + ks * 32)];
#pragma unroll
      for (int nj = 0; nj < 8; nj++) {
        const int krow = nj * 16 + lr;
        bf16x8 bk = *(const bf16x8*)&Kb[krow][swz(krow, kb * 8 + ks * 32)];
        s8[nj] = MFMA16(bk, aq, s8[nj]);   // D[k-token][q-token]
      }
    }
    // ---- per-lane softmax (xor 16, 32); P overwrites own Qb row ----
    {
      float m = s8[0][0];
#pragma unroll
      for (int nj = 0; nj < 8; nj++)
#pragma unroll
        for (int r = 0; r < 4; r++) m = fmaxf(m, s8[nj][r]);
      m = fmaxf(m, __shfl_xor(m, 16));
      m = fmaxf(m, __shfl_xor(m, 32));
      float sum = 0.f;
#pragma unroll
      for (int nj = 0; nj < 8; nj++)
#pragma unroll
        for (int r = 0; r < 4; r++) {
          s8[nj][r] = __expf((s8[nj][r] - m) * scale);
          sum += s8[nj][r];
        }
      sum += __shfl_xor(sum, 16);
      sum += __shfl_xor(sum, 32);
      const float inv = 1.f / sum;
#pragma unroll
      for (int nj = 0; nj < 8; nj++) {
        bf16x4 pp = {f2bf(s8[nj][0] * inv), f2bf(s8[nj][1] * inv),
                     f2bf(s8[nj][2] * inv), f2bf(s8[nj][3] * inv)};
        *(bf16x4*)&Qb[qrow][swz(qrow, nj * 16 + kb * 4)] = pp;
      }
    }

    // ---- O = P V : lane reads own P row (in-wave dep), all Vtb rows ----
    f32x4 o8[8];
#pragma unroll
    for (int i = 0; i < 8; i++) o8[i] = (f32x4){0.f, 0.f, 0.f, 0.f};
#pragma unroll
    for (int ks = 0; ks < 4; ks++) {
      bf16x8 bp = *(const bf16x8*)&Qb[qrow][swz(qrow, kb * 8 + ks * 32)];
#pragma unroll
      for (int mi = 0; mi < 8; mi++) {
        const int vrow = mi * 16 + lr;
        bf16x8 av = *(const bf16x8*)&Vtb[vrow][swz(vrow, kb * 8 + ks * 32)];
        o8[mi] = MFMA16(av, bp, o8[mi]);   // D[chan][q-token]
      }
    }

    __syncthreads();  // C: all waves' S reads of Kb done; O may overwrite

#pragma unroll
    for (int mi = 0; mi < 8; mi++) {
      const int cc = mi * 16 + kb * 4;
      bf16x4 po = {f2bf(o8[mi][0]), f2bf(o8[mi][1]), f2bf(o8[mi][2]), f2bf(o8[mi][3])};
      *(bf16x4*)&Kb[qrow][swz(qrow, cc)] = po;
    }

    __syncthreads();  // D: O complete for all waves

    // ---- proj: out-chans [wid*32, wid*32+32), all tokens ----
    {
      const short* w0 = woT + (size_t)(wid * 32 + lr) * 256 + h * 128 + kb * 8;
      const short* w1 = woT + (size_t)(wid * 32 + 16 + lr) * 256 + h * 128 + kb * 8;
      bf16x8 wa[4], wb2[4];
#pragma unroll
      for (int ks = 0; ks < 4; ks++) {
        wa[ks]  = *(const bf16x8*)(w0 + ks * 32);
        wb2[ks] = *(const bf16x8*)(w1 + ks * 32);
      }
#pragma unroll
      for (int nt = 0; nt < 8; nt++) {
        const int trow = nt * 16 + lr;
#pragma unroll
        for (int ks = 0; ks < 4; ks++) {
          bf16x8 bo = *(const bf16x8*)&Kb[trow][swz(trow, kb * 8 + ks * 32)];
          accp[0][nt] = MFMA16(wa[ks], bo, accp[0][nt]);
          accp[1][nt] = MFMA16(wb2[ks], bo, accp[1][nt]);
        }
      }
    }
  }

  // ---- accb write: token = nt*16+lr, outc = wid*32 + mi2*16 + kb*4 + r ----
#pragma unroll
  for (int mi2 = 0; mi2 < 2; mi2++) {
    const int outc = wid * 32 + mi2 * 16 + kb * 4;
    const float b0 = wob[outc], b1 = wob[outc + 1];
    const float b2 = wob[outc + 2], b3 = wob[outc + 3];
#pragma unroll
    for (int nt = 0; nt < 8; nt++) {
      const int token = tok0 + (nt * 16 + lr) * tstep;
      bf16x4 pv = {f2bf(accp[mi2][nt][0] + b0), f2bf(accp[mi2][nt][1] + b1),
                   f2bf(accp[mi2][nt][2] + b2), f2bf(accp[mi2][nt][3] + b3)};
      *(bf16x4*)(accb + (size_t)token * 256 + outc) = pv;
    }
  }
}

// ---- conv1x1: [relu(a0+a1)|xu|res] @ convT^T -> relu -> ytmp(f32) + BN partials
__global__ __launch_bounds__(256) void k_gemm_conv(const short* __restrict__ accb0,
                                                   const short* __restrict__ accb1,
                                                   const short* __restrict__ xu,
                                                   const float* __restrict__ res,
                                                   const short* __restrict__ Bt,
                                                   float* __restrict__ ytmp,
                                                   float* __restrict__ partial) {
  __shared__ float redS[2][128], redS2[2][128];
  const int tid = threadIdx.x;
  const int lane = tid & 63, wid = tid >> 6;
  const int lr = lane & 15, kb = lane >> 4;
  const int wr = wid >> 1, wc = wid & 1;
  const int m0 = blockIdx.y * 128;
  f32x4 acc[4][4];
#pragma unroll
  for (int i = 0; i < 4; i++)
#pragma unroll
    for (int j = 0; j < 4; j++) acc[i][j] = (f32x4){0.f, 0.f, 0.f, 0.f};
  const short* arow0 = accb0 + (size_t)(m0 + wr * 64 + lr) * 256 + kb * 8;
  const short* arow1 = accb1 + (size_t)(m0 + wr * 64 + lr) * 256 + kb * 8;
  const short* arow2 = xu + (size_t)(m0 + wr * 64 + lr) * 256 + kb * 8;
  const short* brow = Bt + (size_t)(wc * 64 + lr) * 640 + kb * 8;
#pragma unroll
  for (int ks = 0; ks < 8; ks++) {
    bf16x8 a[4], b[4];
#pragma unroll
    for (int mi = 0; mi < 4; mi++) {
      bf16x8 t0 = *(const bf16x8*)(arow0 + (size_t)mi * 16 * 256 + ks * 32);
      bf16x8 t1 = *(const bf16x8*)(arow1 + (size_t)mi * 16 * 256 + ks * 32);
      bf16x8 tv;
#pragma unroll
      for (int u = 0; u < 8; u++) {
        float sv = bf2f(t0[u]) + bf2f(t1[u]);
        tv[u] = f2bf(fmaxf(sv, 0.f));
      }
      a[mi] = tv;
    }
#pragma unroll
    for (int nj = 0; nj < 4; nj++)
      b[nj] = *(const bf16x8*)(brow + (size_t)nj * 16 * 640 + ks * 32);
#pragma unroll
    for (int mi = 0; mi < 4; mi++)
#pragma unroll
      for (int nj = 0; nj < 4; nj++)
        acc[mi][nj] = MFMA16(a[mi], b[nj], acc[mi][nj]);
  }
#pragma unroll
  for (int ks = 8; ks < 16; ks++) {
    bf16x8 a[4], b[4];
#pragma unroll
    for (int mi = 0; mi < 4; mi++)
      a[mi] = *(const bf16x8*)(arow2 + (size_t)mi * 16 * 256 + (ks - 8) * 32);
#pragma unroll
    for (int nj = 0; nj < 4; nj++)
      b[nj] = *(const bf16x8*)(brow + (size_t)nj * 16 * 640 + ks * 32);
#pragma unroll
    for (int mi = 0; mi < 4; mi++)
#pragma unroll
      for (int nj = 0; nj < 4; nj++)
        acc[mi][nj] = MFMA16(a[mi], b[nj], acc[mi][nj]);
  }
  const int bC = (m0 >> 14) * 128;
  const int hh = (m0 >> 7) & 127;
#pragma unroll
  for (int ks = 16; ks < 20; ks++) {
    const int e0 = (ks - 16) * 32 + kb * 8;
    bf16x8 a[4], b[4];
#pragma unroll
    for (int mi = 0; mi < 4; mi++) {
      const int wl = wr * 64 + mi * 16 + lr;
      const float* rp = res + ((size_t)(bC + e0) * 128 + hh) * 128 + wl;
      bf16x8 tv;
#pragma unroll
      for (int u = 0; u < 8; u++) tv[u] = f2bf(rp[(size_t)u * 16384]);
      a[mi] = tv;
    }
#pragma unroll
    for (int nj = 0; nj < 4; nj++)
      b[nj] = *(const bf16x8*)(brow + (size_t)nj * 16 * 640 + ks * 32);
#pragma unroll
    for (int mi = 0; mi < 4; mi++)
#pragma unroll
      for (int nj = 0; nj < 4; nj++)
        acc[mi][nj] = MFMA16(a[mi], b[nj], acc[mi][nj]);
  }
  // epilogue: relu -> f32 ytmp + per-channel partial sums (exact f32)
#pragma unroll
  for (int nj = 0; nj < 4; nj++) {
    float s = 0.f, s2 = 0.f;
    const int c = wc * 64 + nj * 16 + lr;
#pragma unroll
    for (int mi = 0; mi < 4; mi++) {
      const int rbase = m0 + wr * 64 + mi * 16 + kb * 4;
#pragma unroll
      for (int r = 0; r < 4; r++) {
        const float yv = fmaxf(acc[mi][nj][r], 0.f);
        ytmp[(size_t)(rbase + r) * 128 + c] = yv;
        s += yv; s2 += yv * yv;
      }
    }
    s += __shfl_xor(s, 16);  s += __shfl_xor(s, 32);
    s2 += __shfl_xor(s2, 16); s2 += __shfl_xor(s2, 32);
    if (kb == 0) { redS[wr][c] = s; redS2[wr][c] = s2; }
  }
  __syncthreads();
  if (tid < 128) {
    partial[((size_t)blockIdx.y * 128 + tid) * 2]     = redS[0][tid] + redS[1][tid];
    partial[((size_t)blockIdx.y * 128 + tid) * 2 + 1] = redS2[0][tid] + redS2[1][tid];
  }
}

// ---------------- BN stats final reduce ----------------
__global__ __launch_bounds__(128) void k_bnstats2(const float* __restrict__ partial,
                                                  float* __restrict__ stats) {
  const int ch = threadIdx.x;
  float s = 0.f, s2 = 0.f;
  for (int i = 0; i < 512; i++) {
    s  += partial[(size_t)(i * 128 + ch) * 2];
    s2 += partial[(size_t)(i * 128 + ch) * 2 + 1];
  }
  const float mu = s * (1.f / 65536.f);
  const float var = s2 * (1.f / 65536.f) - mu * mu;
  stats[ch * 2] = mu;
  stats[ch * 2 + 1] = rsqrtf(var + 1e-5f);
}

// ---------------- BN apply + transpose to (B,E,H,W), coalesced writes -------
__global__ __launch_bounds__(256) void k_bnout(const float* __restrict__ y,
                                               const float* __restrict__ stats,
                                               const float* __restrict__ gamma,
                                               const float* __restrict__ beta,
                                               float* __restrict__ out) {
  const int bh = blockIdx.x;
  const int b = bh >> 7, h = bh & 127;
  const int w = threadIdx.x & 127, half = threadIdx.x >> 7;
  const float* yp = y + (size_t)(bh * 128 + w) * 128 + half * 64;
  float* op = out + ((size_t)(b * 128) << 14) + h * 128 + w;
#pragma unroll
  for (int e4 = 0; e4 < 16; e4++) {
    f32x4 v = *(const f32x4*)(yp + e4 * 4);
#pragma unroll
    for (int u = 0; u < 4; u++) {
      const int e = half * 64 + e4 * 4 + u;
      const float mu = stats[e * 2], rstd = stats[e * 2 + 1];
      op[(size_t)e << 14] = (v[u] - mu) * rstd * gamma[e] + beta[e];
    }
  }
}

// ---------------- launcher ----------------
extern "C" void kernel_launch(void* const* d_in, const int* in_sizes, int n_in,
                              void* d_out, int out_size, void* d_ws, size_t ws_size,
                              hipStream_t stream) {
  const float* x      = (const float*)d_in[0];
  const float* res    = (const float*)d_in[1];
  const float* wq_h   = (const float*)d_in[2];
  const float* wkv_h  = (const float*)d_in[3];
  const float* wo_h   = (const float*)d_in[4];
  const float* wob_h  = (const float*)d_in[5];
  const float* wq_w   = (const float*)d_in[6];
  const float* wkv_w  = (const float*)d_in[7];
  const float* wo_w   = (const float*)d_in[8];
  const float* wob_w  = (const float*)d_in[9];
  const float* conv_w = (const float*)d_in[10];
  const float* gamma  = (const float*)d_in[11];
  const float* beta   = (const float*)d_in[12];

  char* ws = (char*)d_ws;
  short* wqkvT[2] = {(short*)(ws + 0), (short*)(ws + 393216)};
  short* woT[2]   = {(short*)(ws + 786432), (short*)(ws + 917504)};
  short* convT    = (short*)(ws + 1048576);
  short* xu       = (short*)(ws + 1245184);
  float* ytmp     = (float*)(ws + 34799616);
  float* partial  = (float*)(ws + 68354048);
  float* stats    = (float*)(ws + 68878336);
  short* accb1    = (short*)(ws + 68879360);
  short* accb0    = (short*)d_out;             // dir-0 axial output in d_out
  float* out      = (float*)d_out;

  if (ws_size < 102433792ull)
    fprintf(stderr, "kernel_launch: ws_size %zu too small\n", ws_size);

  // fused weight prep: starts 0,64,192,256,384,448,512; total 592 tiles
  WtAll P;
  P.src[0] = wq_h;  P.dst[0] = wqkvT[0];          P.K[0] = 256; P.N[0] = 256; P.tile0[0] = 0;
  P.src[1] = wkv_h; P.dst[1] = wqkvT[0] + 65536;  P.K[1] = 256; P.N[1] = 512; P.tile0[1] = 64;
  P.src[2] = wq_w;  P.dst[2] = wqkvT[1];          P.K[2] = 256; P.N[2] = 256; P.tile0[2] = 192;
  P.src[3] = wkv_w; P.dst[3] = wqkvT[1] + 65536;  P.K[3] = 256; P.N[3] = 512; P.tile0[3] = 256;
  P.src[4] = wo_h;  P.dst[4] = woT[0];            P.K[4] = 256; P.N[4] = 256; P.tile0[4] = 384;
  P.src[5] = wo_w;  P.dst[5] = woT[1];            P.K[5] = 256; P.N[5] = 256; P.tile0[5] = 448;
  P.src[6] = conv_w;P.dst[6] = convT;             P.K[6] = 640; P.N[6] = 128; P.tile0[6] = 512;
  k_wt_all<<<592, 256, 0, stream>>>(P);

  k_upsample<<<dim3(512, 4), 256, 0, stream>>>(x, xu);

  k_fused<<<dim3(512, 2), 512, 0, stream>>>(xu, wqkvT[0], woT[0],
                                            wob_h, wob_w, accb0, accb1);

  k_gemm_conv<<<dim3(1, 512), 256, 0, stream>>>(accb0, accb1, xu, res, convT,
                                                ytmp, partial);
  k_bnstats2<<<1, 128, 0, stream>>>(partial, stats);
  k_bnout<<<512, 256, 0, stream>>>(ytmp, stats, gamma, beta, out);
}